// Round 3
// baseline (637.540 us; speedup 1.0000x reference)
//
#include <hip/hip_runtime.h>
#include <math.h>

// ---- fixed problem sizes ----
#define NTOK 1024
#define DDIM 1024
#define HEADS 16
#define KVH 4
#define DH 64
#define BSZ 32
#define NSEL 8
#define WBLK 32            // NTOK / BSZ
#define GQ 4               // HEADS / KVH
#define CDIM 2048          // BSZ*DH
#define HIDN 2048
#define QKVD 1536          // (HEADS + 2*KVH)*DH
#define SCALE 0.125f       // DH^-0.5
#define NEGINF (-__builtin_inff())

typedef unsigned short u16;
typedef u16   u16x4  __attribute__((ext_vector_type(4)));
typedef u16   u16x8  __attribute__((ext_vector_type(8)));
typedef short short8 __attribute__((ext_vector_type(8)));
typedef float f32x4  __attribute__((ext_vector_type(4)));

__device__ __forceinline__ u16 f2bf(float f) {
    unsigned u = __float_as_uint(f);
    return (u16)((u + 0x7fffu + ((u >> 16) & 1u)) >> 16);
}
__device__ __forceinline__ float bf2f(u16 h) { return __uint_as_float(((unsigned)h) << 16); }

__device__ __forceinline__ void glds16(const void* g, void* l) {
    __builtin_amdgcn_global_load_lds(
        (const __attribute__((address_space(1))) unsigned int*)g,
        (__attribute__((address_space(3))) unsigned int*)l, 16, 0, 0);
}

// ---------------------------------------------------------------------------
// K1: RMSNorm -> split-bf16 x (GEMM A operand)
// ---------------------------------------------------------------------------
__global__ void rmsnorm_kernel(const float* __restrict__ inp, const float* __restrict__ g,
                               u16* __restrict__ xhi, u16* __restrict__ xlo) {
    int n = blockIdx.x;
    int t = threadIdx.x;            // 256 threads, one float4 each
    float4 v = ((const float4*)(inp + (size_t)n * DDIM))[t];
    float ss = v.x*v.x + v.y*v.y + v.z*v.z + v.w*v.w;
    for (int off = 32; off; off >>= 1) ss += __shfl_down(ss, off);
    __shared__ float red[4];
    if ((t & 63) == 0) red[t >> 6] = ss;
    __syncthreads();
    float tot = red[0] + red[1] + red[2] + red[3];
    float r = 1.f / sqrtf(tot * (1.f / DDIM) + 1e-6f);
    float4 gv = ((const float4*)g)[t];
    float o[4];
    o[0] = v.x * r * gv.x; o[1] = v.y * r * gv.y;
    o[2] = v.z * r * gv.z; o[3] = v.w * r * gv.w;
    u16x4 h, l;
#pragma unroll
    for (int i = 0; i < 4; ++i) {
        u16 hh = f2bf(o[i]);
        h[i] = hh;
        l[i] = f2bf(o[i] - bf2f(hh));
    }
    ((u16x4*)(xhi + (size_t)n * DDIM))[t] = h;
    ((u16x4*)(xlo + (size_t)n * DDIM))[t] = l;
}

// ---------------------------------------------------------------------------
// K2: weight transpose + split to bf16: W[K][N] f32 -> Thi/Tlo [N][K] bf16
// ---------------------------------------------------------------------------
__global__ void transpose_split(const float* __restrict__ W, u16* __restrict__ Thi,
                                u16* __restrict__ Tlo, int K, int N) {
    __shared__ float tile[64][65];
    int k0 = blockIdx.y * 64, n0 = blockIdx.x * 64;
    int t = threadIdx.x;
    int r = t >> 4, c4 = (t & 15) * 4;
#pragma unroll
    for (int p = 0; p < 4; ++p) {
        float4 v = *(const float4*)&W[(size_t)(k0 + r + p * 16) * N + n0 + c4];
        tile[r + p * 16][c4 + 0] = v.x;
        tile[r + p * 16][c4 + 1] = v.y;
        tile[r + p * 16][c4 + 2] = v.z;
        tile[r + p * 16][c4 + 3] = v.w;
    }
    __syncthreads();
    int n = t >> 2, ks = (t & 3) * 16;
    u16x8 h0, h1, l0, l1;
#pragma unroll
    for (int kk = 0; kk < 16; ++kk) {
        float v = tile[ks + kk][n];
        u16 hh = f2bf(v);
        u16 ll = f2bf(v - bf2f(hh));
        if (kk < 8) { h0[kk] = hh; l0[kk] = ll; }
        else        { h1[kk - 8] = hh; l1[kk - 8] = ll; }
    }
    size_t ob = (size_t)(n0 + n) * K + k0 + ks;
    *(u16x8*)&Thi[ob] = h0;
    *(u16x8*)&Thi[ob + 8] = h1;
    if (Tlo) {
        *(u16x8*)&Tlo[ob] = l0;
        *(u16x8*)&Tlo[ob + 8] = l1;
    }
}

// ---------------------------------------------------------------------------
// K2b: pad small weights [K][Xn] (Xn<=64) -> transposed split-bf16 [128][K] + padded bias
// ---------------------------------------------------------------------------
__global__ void pad_small_w(const float* __restrict__ W, const float* __restrict__ b,
                            u16* __restrict__ Thi, u16* __restrict__ Tlo,
                            float* __restrict__ bias_pad, int K, int Xn) {
    int idx = blockIdx.x * 256 + threadIdx.x;   // 128*K
    int k = idx & (K - 1);
    int n = idx >> (31 - __clz(K));
    if (n >= 128) return;
    float v = (n < Xn) ? W[(size_t)k * Xn + n] : 0.f;
    u16 hh = f2bf(v);
    Thi[(size_t)n * K + k] = hh;
    Tlo[(size_t)n * K + k] = f2bf(v - bf2f(hh));
    if (idx < 128) bias_pad[idx] = (idx < Xn) ? b[idx] : 0.f;
}

// ---------------------------------------------------------------------------
// K3: MFMA GEMM, C = act(A @ Bt^T + bias). A: [M][K] bf16 hi/lo, Bt: [N][K] bf16 hi/lo.
// 128x128 tile, 256 threads (4 waves). SPLIT=3: 3-MFMA split-bf16 (~f32 accurate).
// OUTSPLIT=1: emit split-bf16 (Chi/Clo) instead of f32 C.
// ACT: 0 none, 1 relu, 2 sigmoid
// ---------------------------------------------------------------------------
template<int SPLIT, int ACT, int OUTSPLIT>
__global__ __launch_bounds__(256, 1)
void gemm_mfma(const u16* __restrict__ Ahi0, const u16* __restrict__ Alo0,
               const u16* __restrict__ Bthi0, const u16* __restrict__ Btlo0,
               const float* __restrict__ bias0, float* __restrict__ C0,
               u16* __restrict__ Chi0, u16* __restrict__ Clo0,
               const u16* __restrict__ Ahi1, const u16* __restrict__ Alo1,
               const u16* __restrict__ Bthi1, const u16* __restrict__ Btlo1,
               const float* __restrict__ bias1, float* __restrict__ C1,
               u16* __restrict__ Chi1, u16* __restrict__ Clo1,
               int M, int N, int K) {
    const u16* Ahi  = blockIdx.z ? Ahi1  : Ahi0;
    const u16* Alo  = blockIdx.z ? Alo1  : Alo0;
    const u16* Bthi = blockIdx.z ? Bthi1 : Bthi0;
    const u16* Btlo = blockIdx.z ? Btlo1 : Btlo0;
    const float* bias = blockIdx.z ? bias1 : bias0;
    float* C   = blockIdx.z ? C1 : C0;
    u16*   Chi = blockIdx.z ? Chi1 : Chi0;
    u16*   Clo = blockIdx.z ? Clo1 : Clo0;

    __shared__ u16 smA[2][8 * 64 * 8];   // [hi/lo][(group*64+lane)*8]
    __shared__ u16 smB[2][8 * 64 * 8];

    int tid = threadIdx.x;
    int w = tid >> 6, L = tid & 63;
    int m15 = L & 15, q = L >> 4;
    int rowbase = blockIdx.y * 128;
    int colbase = blockIdx.x * 128;

    const u16* pAh0 = Ahi + (size_t)(rowbase + (2 * w) * 16 + m15) * K + q * 8;
    const u16* pAh1 = pAh0 + (size_t)16 * K;
    const u16* pAl0 = Alo + (size_t)(rowbase + (2 * w) * 16 + m15) * K + q * 8;
    const u16* pAl1 = pAl0 + (size_t)16 * K;
    const u16* pBh0 = Bthi + (size_t)(colbase + (2 * w) * 16 + m15) * K + q * 8;
    const u16* pBh1 = pBh0 + (size_t)16 * K;
    const u16* pBl0 = Btlo + (size_t)(colbase + (2 * w) * 16 + m15) * K + q * 8;
    const u16* pBl1 = pBl0 + (size_t)16 * K;
    u16* dAh0 = &smA[0][(2 * w) * 64 * 8];
    u16* dAh1 = &smA[0][(2 * w + 1) * 64 * 8];
    u16* dAl0 = &smA[1][(2 * w) * 64 * 8];
    u16* dAl1 = &smA[1][(2 * w + 1) * 64 * 8];
    u16* dBh0 = &smB[0][(2 * w) * 64 * 8];
    u16* dBh1 = &smB[0][(2 * w + 1) * 64 * 8];
    u16* dBl0 = &smB[1][(2 * w) * 64 * 8];
    u16* dBl1 = &smB[1][(2 * w + 1) * 64 * 8];

    int aw = w & 1, bw = w >> 1;
    f32x4 acc[4][4];
#pragma unroll
    for (int i = 0; i < 4; ++i)
#pragma unroll
        for (int j = 0; j < 4; ++j) acc[i][j] = (f32x4){0.f, 0.f, 0.f, 0.f};

    for (int k0 = 0; k0 < K; k0 += 32) {
        glds16(pAh0 + k0, dAh0);
        glds16(pAh1 + k0, dAh1);
        glds16(pBh0 + k0, dBh0);
        glds16(pBh1 + k0, dBh1);
        if constexpr (SPLIT == 3) {
            glds16(pAl0 + k0, dAl0);
            glds16(pAl1 + k0, dAl1);
            glds16(pBl0 + k0, dBl0);
            glds16(pBl1 + k0, dBl1);
        }
        __syncthreads();

        short8 ah[4], bh[4];
#pragma unroll
        for (int i = 0; i < 4; ++i) {
            ah[i] = *(const short8*)&smA[0][((aw * 4 + i) * 64 + L) * 8];
            bh[i] = *(const short8*)&smB[0][((bw * 4 + i) * 64 + L) * 8];
        }
        if constexpr (SPLIT == 3) {
            short8 al[4], bl[4];
#pragma unroll
            for (int i = 0; i < 4; ++i) {
                al[i] = *(const short8*)&smA[1][((aw * 4 + i) * 64 + L) * 8];
                bl[i] = *(const short8*)&smB[1][((bw * 4 + i) * 64 + L) * 8];
            }
#pragma unroll
            for (int i = 0; i < 4; ++i)
#pragma unroll
                for (int j = 0; j < 4; ++j) {
                    acc[i][j] = __builtin_amdgcn_mfma_f32_16x16x32_bf16(ah[i], bl[j], acc[i][j], 0, 0, 0);
                    acc[i][j] = __builtin_amdgcn_mfma_f32_16x16x32_bf16(al[i], bh[j], acc[i][j], 0, 0, 0);
                    acc[i][j] = __builtin_amdgcn_mfma_f32_16x16x32_bf16(ah[i], bh[j], acc[i][j], 0, 0, 0);
                }
        } else {
#pragma unroll
            for (int i = 0; i < 4; ++i)
#pragma unroll
                for (int j = 0; j < 4; ++j)
                    acc[i][j] = __builtin_amdgcn_mfma_f32_16x16x32_bf16(ah[i], bh[j], acc[i][j], 0, 0, 0);
        }
        __syncthreads();
    }

#pragma unroll
    for (int i = 0; i < 4; ++i) {
        int row = rowbase + aw * 64 + i * 16 + q * 4;
#pragma unroll
        for (int j = 0; j < 4; ++j) {
            int col = colbase + bw * 64 + j * 16 + m15;
            float bv = bias ? bias[col] : 0.f;
#pragma unroll
            for (int r = 0; r < 4; ++r) {
                float v = acc[i][j][r] + bv;
                if (ACT == 1) v = fmaxf(v, 0.f);
                if (ACT == 2) v = 1.f / (1.f + expf(-v));
                if constexpr (OUTSPLIT) {
                    u16 hh = f2bf(v);
                    Chi[(size_t)(row + r) * N + col] = hh;
                    Clo[(size_t)(row + r) * N + col] = f2bf(v - bf2f(hh));
                } else {
                    C[(size_t)(row + r) * N + col] = v;
                }
            }
        }
    }
}

// ---------------------------------------------------------------------------
// K5: build compress-MLP inputs, split-bf16 out
// ---------------------------------------------------------------------------
__global__ void build_cmlp_in(const float* __restrict__ qkv, const float* __restrict__ k_pos,
                              const float* __restrict__ v_pos,
                              u16* __restrict__ ckhi, u16* __restrict__ cklo,
                              u16* __restrict__ cvhi, u16* __restrict__ cvlo) {
    int idx = blockIdx.x * 256 + threadIdx.x;   // 4*32*32*64 = 262144
    int d = idx & 63;
    int p = (idx >> 6) & 31;
    int w = (idx >> 11) & 31;
    int h = idx >> 16;
    int nn = w * BSZ + p;
    float kv = qkv[(size_t)nn * QKVD + (HEADS + h) * DH + d] + k_pos[(h * BSZ + p) * DH + d];
    float vv = qkv[(size_t)nn * QKVD + (HEADS + KVH + h) * DH + d] + v_pos[(h * BSZ + p) * DH + d];
    u16 kh = f2bf(kv), vh = f2bf(vv);
    ckhi[idx] = kh; cklo[idx] = f2bf(kv - bf2f(kh));
    cvhi[idx] = vh; cvlo[idx] = f2bf(vv - bf2f(vh));
}

// ---------------------------------------------------------------------------
// K6: assemble ck/cv = concat(mem_kv, mlp_out[128-padded]) : [KVH][MEM+W][DH]
// ---------------------------------------------------------------------------
__global__ void assemble_ckcv(const float* __restrict__ mem_kv, const float* __restrict__ ckp,
                              const float* __restrict__ cvp,
                              float* __restrict__ ck, float* __restrict__ cv) {
    int idx = blockIdx.x * 256 + threadIdx.x;   // 4*33*64 = 8448
    if (idx >= KVH * 33 * DH) return;
    int d = idx & 63;
    int j = (idx >> 6) % 33;
    int h = idx / (33 * 64);
    if (j == 0) {
        ck[idx] = mem_kv[(0 * KVH + h) * DH + d];
        cv[idx] = mem_kv[(1 * KVH + h) * DH + d];
    } else {
        ck[idx] = ckp[(size_t)(h * WBLK + (j - 1)) * 128 + d];
        cv[idx] = cvp[(size_t)(h * WBLK + (j - 1)) * 128 + d];
    }
}

// ---------------------------------------------------------------------------
// K7: interleaved rotary for q (16 heads) and k (4 heads)
// ---------------------------------------------------------------------------
__global__ void rotary_kernel(const float* __restrict__ qkv,
                              float* __restrict__ qr, float* __restrict__ kr) {
    int idx = blockIdx.x * 256 + threadIdx.x;   // 20*1024*32 = 655360
    int i = idx & 31;
    int n = (idx >> 5) & 1023;
    int hd = idx >> 15;
    if (hd >= HEADS + KVH) return;
    float inv = powf(10000.f, -(float)i / 32.f);
    float fr = (float)n * inv;
    float c = cosf(fr), s = sinf(fr);
    const float* src; float* dst;
    if (hd < HEADS) { src = qkv + (size_t)n * QKVD + hd * DH;          dst = qr + ((size_t)hd * NTOK + n) * DH; }
    else { int h = hd - HEADS;
           src = qkv + (size_t)n * QKVD + (HEADS + h) * DH;            dst = kr + ((size_t)h * NTOK + n) * DH; }
    float x0 = src[2 * i], x1 = src[2 * i + 1];
    dst[2 * i]     = x0 * c - x1 * s;
    dst[2 * i + 1] = x1 * c + x0 * s;
}

// ---------------------------------------------------------------------------
// K8: compressed attention + importance softmax + top-k selection.
// ---------------------------------------------------------------------------
__global__ void cattn_kernel(const float* __restrict__ qkv, const float* __restrict__ ck,
                             const float* __restrict__ cv, float* __restrict__ c_out,
                             int* __restrict__ sel, int* __restrict__ selmask) {
    int n = blockIdx.x, h = blockIdx.y;
    int lane = threadIdx.x;          // 0..63, single wave
    __shared__ float cks[33 * 65];
    __shared__ float cvs[33 * 65];
    __shared__ float qs[4 * 64];
    __shared__ float sims[4 * 33];
    __shared__ float attn_s[64];

    for (int t = lane; t < 33 * 64; t += 64) {
        int j = t >> 6, d = t & 63;
        cks[j * 65 + d] = ck[(size_t)h * 33 * 64 + t];
        cvs[j * 65 + d] = cv[(size_t)h * 33 * 64 + t];
    }
#pragma unroll
    for (int g = 0; g < GQ; ++g)
        qs[g * 64 + lane] = qkv[(size_t)n * QKVD + (h * GQ + g) * DH + lane];
    __syncthreads();

    for (int g = 0; g < GQ; ++g) {
        float s = NEGINF;
        if (lane < 33) {
            float acc = 0.f;
#pragma unroll
            for (int d = 0; d < 64; ++d) acc = fmaf(qs[g * 64 + d], cks[lane * 65 + d], acc);
            s = acc * SCALE;
            sims[g * 33 + lane] = s;
        }
        float m = s;
        for (int off = 32; off; off >>= 1) m = fmaxf(m, __shfl_xor(m, off));
        float e = (lane < 33) ? expf(s - m) : 0.f;
        float sum = e;
        for (int off = 32; off; off >>= 1) sum += __shfl_xor(sum, off);
        attn_s[lane] = (lane < 33) ? e / sum : 0.f;
        __syncthreads();
        float acc2 = 0.f;
#pragma unroll
        for (int j = 0; j < 33; ++j) acc2 = fmaf(attn_s[j], cvs[j * 65 + lane], acc2);
        c_out[(((size_t)(h * GQ + g)) * NTOK + n) * DH + lane] = acc2;
        __syncthreads();
    }

    float ival = NEGINF;
    if (lane < 32)
        ival = 0.25f * (sims[0 * 33 + 1 + lane] + sims[1 * 33 + 1 + lane] +
                        sims[2 * 33 + 1 + lane] + sims[3 * 33 + 1 + lane]);
    float m = ival;
    for (int off = 32; off; off >>= 1) m = fmaxf(m, __shfl_xor(m, off));
    float e = (lane < 32) ? expf(ival - m) : 0.f;
    float sum = e;
    for (int off = 32; off; off >>= 1) sum += __shfl_xor(sum, off);
    float p = (lane < 32) ? e / sum : NEGINF;

    float v = p;
    int base = (h * NTOK + n) * 9;
    for (int t = 0; t < NSEL; ++t) {
        float bv = v; int bi = lane;
        for (int off = 32; off; off >>= 1) {
            float ov = __shfl_xor(bv, off);
            int   oi = __shfl_xor(bi, off);
            if (ov > bv || (ov == bv && oi < bi)) { bv = ov; bi = oi; }
        }
        if (lane == 0) { sel[base + t] = bi; selmask[base + t] = (bv > 1e-10f) ? 1 : 0; }
        if (lane == bi) v = NEGINF;
    }
    if (lane == 0) { sel[base + NSEL] = n >> 5; selmask[base + NSEL] = 1; }
}

// ---------------------------------------------------------------------------
// K9: fine (selected-block) attention.
// ---------------------------------------------------------------------------
__global__ void fattn_kernel(const float* __restrict__ qr, const float* __restrict__ kr,
                             const float* __restrict__ qkv, const int* __restrict__ sel,
                             const int* __restrict__ selmask, float* __restrict__ f_out) {
    int n = blockIdx.x, h = blockIdx.y;
    int tid = threadIdx.x;           // 256
    __shared__ float qs[4 * 64];
    __shared__ float kvs[32 * 65];
    __shared__ float sims[4 * 288];
    __shared__ int sel_s[9], msk_s[9];

    if (tid < 9) {
        sel_s[tid] = sel[(h * NTOK + n) * 9 + tid];
        msk_s[tid] = selmask[(h * NTOK + n) * 9 + tid];
    }
    qs[tid] = qr[(((size_t)(h * GQ + (tid >> 6))) * NTOK + n) * DH + (tid & 63)];
    __syncthreads();

    for (int b = 0; b < 9; ++b) {
        int blk = sel_s[b];
        for (int t = tid; t < BSZ * DH; t += 256) {
            int j = t >> 6, d = t & 63;
            kvs[j * 65 + d] = kr[((size_t)h * NTOK + blk * BSZ + j) * DH + d];
        }
        __syncthreads();
        if (tid < 128) {
            int g = tid >> 5, j = tid & 31;
            float s;
            if (msk_s[b]) {
                float acc = 0.f;
#pragma unroll
                for (int d = 0; d < 64; ++d) acc = fmaf(qs[g * 64 + d], kvs[j * 65 + d], acc);
                s = acc * SCALE;
            } else s = -3.402823466e+38f;
            sims[g * 288 + b * 32 + j] = s;
        }
        __syncthreads();
    }

    {
        int g = tid >> 6, lane = tid & 63;
        float m = NEGINF;
        for (int t = lane; t < 288; t += 64) m = fmaxf(m, sims[g * 288 + t]);
        for (int off = 32; off; off >>= 1) m = fmaxf(m, __shfl_xor(m, off));
        float ev[5];
        int cnt = 0;
        float sum = 0.f;
        for (int t = lane; t < 288; t += 64) { float ee = expf(sims[g * 288 + t] - m); ev[cnt++] = ee; sum += ee; }
        for (int off = 32; off; off >>= 1) sum += __shfl_xor(sum, off);
        float inv = 1.f / sum;
        cnt = 0;
        for (int t = lane; t < 288; t += 64) sims[g * 288 + t] = ev[cnt++] * inv;
    }
    __syncthreads();

    int g = tid >> 6, d = tid & 63;
    float acc = 0.f;
    for (int b = 0; b < 9; ++b) {
        int blk = sel_s[b];
        for (int t = tid; t < BSZ * DH; t += 256) {
            int j = t >> 6, dd = t & 63;
            kvs[j * 65 + dd] = qkv[((size_t)(blk * BSZ + j)) * QKVD + (HEADS + KVH + h) * DH + dd];
        }
        __syncthreads();
#pragma unroll
        for (int j = 0; j < 32; ++j) acc = fmaf(sims[g * 288 + b * 32 + j], kvs[j * 65 + d], acc);
        __syncthreads();
    }
    f_out[(((size_t)(h * GQ + g)) * NTOK + n) * DH + d] = acc;
}

// ---------------------------------------------------------------------------
// K10: gated mix -> split-bf16 (A operand of out-proj). gates in [N][128] padded.
// ---------------------------------------------------------------------------
__global__ void mix_kernel(const float* __restrict__ gates, const float* __restrict__ c_out,
                           const float* __restrict__ f_out,
                           u16* __restrict__ mixhi, u16* __restrict__ mixlo) {
    int idx = blockIdx.x * 256 + threadIdx.x;   // 1024*16*64
    int d = idx & 63;
    int hd = (idx >> 6) & 15;
    int n = idx >> 10;
    float g0 = gates[(size_t)n * 128 + hd * 2];
    float g1 = gates[(size_t)n * 128 + hd * 2 + 1];
    size_t hoff = (((size_t)hd) * NTOK + n) * DH + d;
    float v = g0 * c_out[hoff] + g1 * f_out[hoff];
    u16 hh = f2bf(v);
    mixhi[(size_t)n * DDIM + hd * DH + d] = hh;
    mixlo[(size_t)n * DDIM + hd * DH + d] = f2bf(v - bf2f(hh));
}

// ---------------------------------------------------------------------------
extern "C" void kernel_launch(void* const* d_in, const int* in_sizes, int n_in,
                              void* d_out, int out_size, void* d_ws, size_t ws_size,
                              hipStream_t stream) {
    const float* inp    = (const float*)d_in[0];
    const float* g_norm = (const float*)d_in[1];
    const float* w_qkv  = (const float*)d_in[2];
    const float* mem_kv = (const float*)d_in[3];
    const float* k_pos  = (const float*)d_in[4];
    const float* v_pos  = (const float*)d_in[5];
    const float* k_w1   = (const float*)d_in[6];
    const float* k_b1   = (const float*)d_in[7];
    const float* k_w2   = (const float*)d_in[8];
    const float* k_b2   = (const float*)d_in[9];
    const float* v_w1   = (const float*)d_in[10];
    const float* v_b1   = (const float*)d_in[11];
    const float* v_w2   = (const float*)d_in[12];
    const float* v_b2   = (const float*)d_in[13];
    const float* gate_w = (const float*)d_in[14];
    const float* gate_b = (const float*)d_in[15];
    const float* w_out  = (const float*)d_in[16];
    float* out = (float*)d_out;

    char* wsb = (char*)d_ws;
    size_t off = 0;
    auto alloc = [&](size_t bytes) -> void* {
        void* p = wsb + off;
        off = (off + bytes + 255) & ~(size_t)255;
        return p;
    };
    u16*   xhi    = (u16*)  alloc((size_t)NTOK * DDIM * 2);
    u16*   xlo    = (u16*)  alloc((size_t)NTOK * DDIM * 2);
    float* qkvb   = (float*)alloc((size_t)NTOK * QKVD * 4);
    u16*   wqThi  = (u16*)  alloc((size_t)QKVD * DDIM * 2);
    u16*   wqTlo  = (u16*)  alloc((size_t)QKVD * DDIM * 2);
    u16*   kw1Thi = (u16*)  alloc((size_t)HIDN * CDIM * 2);
    u16*   kw1Tlo = (u16*)  alloc((size_t)HIDN * CDIM * 2);
    u16*   vw1Thi = (u16*)  alloc((size_t)HIDN * CDIM * 2);
    u16*   vw1Tlo = (u16*)  alloc((size_t)HIDN * CDIM * 2);
    u16*   woThi  = (u16*)  alloc((size_t)DDIM * DDIM * 2);
    u16*   gwThi  = (u16*)  alloc((size_t)128 * DDIM * 2);
    u16*   gwTlo  = (u16*)  alloc((size_t)128 * DDIM * 2);
    float* gbp    = (float*)alloc(128 * 4);
    u16*   kw2Thi = (u16*)  alloc((size_t)128 * HIDN * 2);
    u16*   kw2Tlo = (u16*)  alloc((size_t)128 * HIDN * 2);
    float* kb2p   = (float*)alloc(128 * 4);
    u16*   vw2Thi = (u16*)  alloc((size_t)128 * HIDN * 2);
    u16*   vw2Tlo = (u16*)  alloc((size_t)128 * HIDN * 2);
    float* vb2p   = (float*)alloc(128 * 4);
    u16*   cinkhi = (u16*)  alloc((size_t)128 * CDIM * 2);
    u16*   cinklo = (u16*)  alloc((size_t)128 * CDIM * 2);
    u16*   cinvhi = (u16*)  alloc((size_t)128 * CDIM * 2);
    u16*   cinvlo = (u16*)  alloc((size_t)128 * CDIM * 2);
    u16*   hidkhi = (u16*)  alloc((size_t)128 * HIDN * 2);
    u16*   hidklo = (u16*)  alloc((size_t)128 * HIDN * 2);
    u16*   hidvhi = (u16*)  alloc((size_t)128 * HIDN * 2);
    u16*   hidvlo = (u16*)  alloc((size_t)128 * HIDN * 2);
    float* ckp    = (float*)alloc((size_t)128 * 128 * 4);
    float* cvp    = (float*)alloc((size_t)128 * 128 * 4);
    float* ck     = (float*)alloc((size_t)KVH * 33 * DH * 4);
    float* cv     = (float*)alloc((size_t)KVH * 33 * DH * 4);
    float* qr     = (float*)alloc((size_t)HEADS * NTOK * DH * 4);
    float* kr     = (float*)alloc((size_t)KVH * NTOK * DH * 4);
    float* c_out  = (float*)alloc((size_t)HEADS * NTOK * DH * 4);
    float* f_out  = (float*)alloc((size_t)HEADS * NTOK * DH * 4);
    float* gates  = (float*)alloc((size_t)NTOK * 128 * 4);
    int*   sel    = (int*)  alloc((size_t)KVH * NTOK * 9 * 4);
    int*   selmask= (int*)  alloc((size_t)KVH * NTOK * 9 * 4);
    u16*   mixhi  = (u16*)  alloc((size_t)NTOK * DDIM * 2);
    u16*   mixlo  = (u16*)  alloc((size_t)NTOK * DDIM * 2);

    // weight transposes + splits (independent of activations)
    transpose_split<<<dim3(QKVD / 64, DDIM / 64), 256, 0, stream>>>(w_qkv, wqThi, wqTlo, DDIM, QKVD);
    transpose_split<<<dim3(HIDN / 64, CDIM / 64), 256, 0, stream>>>(k_w1, kw1Thi, kw1Tlo, CDIM, HIDN);
    transpose_split<<<dim3(HIDN / 64, CDIM / 64), 256, 0, stream>>>(v_w1, vw1Thi, vw1Tlo, CDIM, HIDN);
    transpose_split<<<dim3(DDIM / 64, DDIM / 64), 256, 0, stream>>>(w_out, woThi, nullptr, DDIM, DDIM);
    pad_small_w<<<(128 * DDIM) / 256, 256, 0, stream>>>(gate_w, gate_b, gwThi, gwTlo, gbp, DDIM, 32);
    pad_small_w<<<(128 * HIDN) / 256, 256, 0, stream>>>(k_w2, k_b2, kw2Thi, kw2Tlo, kb2p, HIDN, 64);
    pad_small_w<<<(128 * HIDN) / 256, 256, 0, stream>>>(v_w2, v_b2, vw2Thi, vw2Tlo, vb2p, HIDN, 64);

    // 1. RMSNorm (split-bf16 x)
    rmsnorm_kernel<<<NTOK, 256, 0, stream>>>(inp, g_norm, xhi, xlo);
    // 2. qkv = x @ w_qkv   (split-bf16, ~f32 accurate)
    gemm_mfma<3, 0, 0><<<dim3(QKVD / 128, NTOK / 128, 1), 256, 0, stream>>>(
        xhi, xlo, wqThi, wqTlo, nullptr, qkvb, nullptr, nullptr,
        xhi, xlo, wqThi, wqTlo, nullptr, qkvb, nullptr, nullptr, NTOK, QKVD, DDIM);
    // 3. gates = sigmoid(x @ gate_w + gate_b)  (N padded to 128)
    gemm_mfma<3, 2, 0><<<dim3(1, NTOK / 128, 1), 256, 0, stream>>>(
        xhi, xlo, gwThi, gwTlo, gbp, gates, nullptr, nullptr,
        xhi, xlo, gwThi, gwTlo, gbp, gates, nullptr, nullptr, NTOK, 128, DDIM);
    // 4. compress-MLP inputs
    build_cmlp_in<<<(KVH * WBLK * BSZ * DH) / 256, 256, 0, stream>>>(
        qkvb, k_pos, v_pos, cinkhi, cinklo, cinvhi, cinvlo);
    // 5. MLP layer 1 (relu+bias), split-bf16 out, k & v batched over z
    gemm_mfma<3, 1, 1><<<dim3(HIDN / 128, 1, 2), 256, 0, stream>>>(
        cinkhi, cinklo, kw1Thi, kw1Tlo, k_b1, nullptr, hidkhi, hidklo,
        cinvhi, cinvlo, vw1Thi, vw1Tlo, v_b1, nullptr, hidvhi, hidvlo, 128, HIDN, CDIM);
    // 6. MLP layer 2 (N padded to 128), k & v batched over z
    gemm_mfma<3, 0, 0><<<dim3(1, 1, 2), 256, 0, stream>>>(
        hidkhi, hidklo, kw2Thi, kw2Tlo, kb2p, ckp, nullptr, nullptr,
        hidvhi, hidvlo, vw2Thi, vw2Tlo, vb2p, cvp, nullptr, nullptr, 128, 128, HIDN);
    // 7. concat mem_kv
    assemble_ckcv<<<(KVH * 33 * DH + 255) / 256, 256, 0, stream>>>(mem_kv, ckp, cvp, ck, cv);
    // 8. rotary
    rotary_kernel<<<((HEADS + KVH) * NTOK * 32) / 256, 256, 0, stream>>>(qkvb, qr, kr);
    // 9. compressed attention + selection
    cattn_kernel<<<dim3(NTOK, KVH), 64, 0, stream>>>(qkvb, ck, cv, c_out, sel, selmask);
    // 10. fine attention
    fattn_kernel<<<dim3(NTOK, KVH), 256, 0, stream>>>(qr, kr, qkvb, sel, selmask, f_out);
    // 11. gated mix (-> bf16 hi/lo)
    mix_kernel<<<(NTOK * HEADS * DH) / 256, 256, 0, stream>>>(gates, c_out, f_out, mixhi, mixlo);
    // 12. output projection (plain bf16 is plenty here)
    gemm_mfma<1, 0, 0><<<dim3(DDIM / 128, NTOK / 128, 1), 256, 0, stream>>>(
        mixhi, mixhi, woThi, woThi, nullptr, out, nullptr, nullptr,
        mixhi, mixhi, woThi, woThi, nullptr, out, nullptr, nullptr, NTOK, DDIM, DDIM);
}

// Round 4
// 387.982 us; speedup vs baseline: 1.6432x; 1.6432x over previous
//
#include <hip/hip_runtime.h>
#include <math.h>

// ---- fixed problem sizes ----
#define NTOK 1024
#define DDIM 1024
#define HEADS 16
#define KVH 4
#define DH 64
#define BSZ 32
#define NSEL 8
#define WBLK 32            // NTOK / BSZ
#define GQ 4               // HEADS / KVH
#define CDIM 2048          // BSZ*DH
#define HIDN 2048
#define QKVD 1536          // (HEADS + 2*KVH)*DH
#define SCALE 0.125f       // DH^-0.5
#define NEGINF (-__builtin_inff())

typedef unsigned short u16;
typedef u16   u16x8  __attribute__((ext_vector_type(8)));
typedef short short8 __attribute__((ext_vector_type(8)));
typedef float f32x4  __attribute__((ext_vector_type(4)));

__device__ __forceinline__ u16 f2bf(float f) {
    unsigned u = __float_as_uint(f);
    return (u16)((u + 0x7fffu + ((u >> 16) & 1u)) >> 16);
}
__device__ __forceinline__ float bf2f(u16 h) { return __uint_as_float(((unsigned)h) << 16); }

__device__ __forceinline__ void glds16(const void* g, void* l) {
    __builtin_amdgcn_global_load_lds(
        (const __attribute__((address_space(1))) unsigned int*)g,
        (__attribute__((address_space(3))) unsigned int*)l, 16, 0, 0);
}

// element offset (in u16) of the 8-element lane-slot for (row, k..k+7) in the
// MFMA-fragment-tiled layout: 16-row x 32-k tiles, 1KB each, contiguous.
__device__ __forceinline__ size_t tiled_off(int row, int k, int K) {
    return ((size_t)((row >> 4) * (K >> 5) + (k >> 5)) * 64 +
            ((row & 15) | (((k >> 3) & 3) << 4))) * 8;
}

// ---------------------------------------------------------------------------
// K1: RMSNorm -> split-bf16 x in TILED layout (K=DDIM). 2 rows per 256-thr block.
// ---------------------------------------------------------------------------
__global__ void rmsnorm_kernel(const float* __restrict__ inp, const float* __restrict__ g,
                               u16* __restrict__ xhi, u16* __restrict__ xlo) {
    int t = threadIdx.x;
    int half = t >> 7, tid = t & 127;
    int n = blockIdx.x * 2 + half;
    const float4* row = (const float4*)(inp + (size_t)n * DDIM);
    float4 v0 = row[tid * 2], v1 = row[tid * 2 + 1];
    float ss = v0.x*v0.x + v0.y*v0.y + v0.z*v0.z + v0.w*v0.w
             + v1.x*v1.x + v1.y*v1.y + v1.z*v1.z + v1.w*v1.w;
    for (int off = 32; off; off >>= 1) ss += __shfl_down(ss, off);
    __shared__ float red[4];
    if ((t & 63) == 0) red[t >> 6] = ss;
    __syncthreads();
    float tot = red[half * 2] + red[half * 2 + 1];
    float r = 1.f / sqrtf(tot * (1.f / DDIM) + 1e-6f);
    const float4* gp = (const float4*)g;
    float4 g0 = gp[tid * 2], g1 = gp[tid * 2 + 1];
    float o[8] = { v0.x*r*g0.x, v0.y*r*g0.y, v0.z*r*g0.z, v0.w*r*g0.w,
                   v1.x*r*g1.x, v1.y*r*g1.y, v1.z*r*g1.z, v1.w*r*g1.w };
    u16x8 h, l;
#pragma unroll
    for (int i = 0; i < 8; ++i) {
        u16 hh = f2bf(o[i]);
        h[i] = hh;
        l[i] = f2bf(o[i] - bf2f(hh));
    }
    size_t ob = tiled_off(n, tid * 8, DDIM);
    *(u16x8*)&xhi[ob] = h;
    *(u16x8*)&xlo[ob] = l;
}

// ---------------------------------------------------------------------------
// K2: weight transpose + split: W[K][N] f32 -> tiled Bt[N][K] bf16 hi/lo
// ---------------------------------------------------------------------------
__global__ void transpose_split(const float* __restrict__ W, u16* __restrict__ Thi,
                                u16* __restrict__ Tlo, int K, int N) {
    __shared__ float tile[64][65];
    int k0 = blockIdx.y * 64, n0 = blockIdx.x * 64;
    int t = threadIdx.x;
    int r = t >> 4, c4 = (t & 15) * 4;
#pragma unroll
    for (int p = 0; p < 4; ++p) {
        float4 v = *(const float4*)&W[(size_t)(k0 + r + p * 16) * N + n0 + c4];
        tile[r + p * 16][c4 + 0] = v.x;
        tile[r + p * 16][c4 + 1] = v.y;
        tile[r + p * 16][c4 + 2] = v.z;
        tile[r + p * 16][c4 + 3] = v.w;
    }
    __syncthreads();
    int n = t >> 2, ks = (t & 3) * 16;
#pragma unroll
    for (int c = 0; c < 2; ++c) {
        u16x8 h, l;
#pragma unroll
        for (int j = 0; j < 8; ++j) {
            float v = tile[ks + c * 8 + j][n];
            u16 hh = f2bf(v);
            h[j] = hh;
            l[j] = f2bf(v - bf2f(hh));
        }
        size_t ob = tiled_off(n0 + n, k0 + ks + c * 8, K);
        *(u16x8*)&Thi[ob] = h;
        if (Tlo) *(u16x8*)&Tlo[ob] = l;
    }
}

// ---------------------------------------------------------------------------
// K2b: pad small weights [K][Xn] (Xn<=64) -> tiled split-bf16 [128][K] + padded bias
// ---------------------------------------------------------------------------
__global__ void pad_small_tiled(const float* __restrict__ W, const float* __restrict__ b,
                                u16* __restrict__ Thi, u16* __restrict__ Tlo,
                                float* __restrict__ bias_pad, int K, int Xn, int KLOG) {
    int idx = blockIdx.x * 256 + threadIdx.x;   // 128 * K/8
    int k = (idx & ((K >> 3) - 1)) * 8;
    int n = idx >> (KLOG - 3);
    if (n >= 128) return;
    u16x8 h, l;
#pragma unroll
    for (int j = 0; j < 8; ++j) {
        float v = (n < Xn) ? W[(size_t)(k + j) * Xn + n] : 0.f;
        u16 hh = f2bf(v);
        h[j] = hh;
        l[j] = f2bf(v - bf2f(hh));
    }
    size_t ob = tiled_off(n, k, K);
    *(u16x8*)&Thi[ob] = h;
    *(u16x8*)&Tlo[ob] = l;
    if (k == 0) bias_pad[n] = (n < Xn) ? b[n] : 0.f;
}

// ---------------------------------------------------------------------------
// K3: tiled MFMA GEMM with software pipeline + optional split-K.
// A,Bt in fragment-tiled bf16 hi/lo. 128x128 tile, 256 thr, 4 waves.
// SPLIT=3: 3-MFMA split-bf16; SPLIT=1: plain bf16.
// FINAL=1: apply bias/ACT, write C f32 [M][N]. FINAL=0: write partial slice s.
// gridDim.z = batches * S; batch selects pointer set.
// Pipeline: prefetch for it+1 issued AFTER __syncthreads(), so the barrier's
// vmcnt(0) drain waits on exactly the loads compute(it) needs -> overlap.
// ---------------------------------------------------------------------------
template<int SPLIT, int ACT, int FINAL>
__global__ __launch_bounds__(256, 1)
void gemm_tiled(const u16* __restrict__ Ahi0, const u16* __restrict__ Alo0,
                const u16* __restrict__ Bhi0, const u16* __restrict__ Blo0,
                const float* __restrict__ bias0, float* __restrict__ C0,
                const u16* __restrict__ Ahi1, const u16* __restrict__ Alo1,
                const u16* __restrict__ Bhi1, const u16* __restrict__ Blo1,
                const float* __restrict__ bias1, float* __restrict__ C1,
                int M, int N, int K, int S) {
    int batch = blockIdx.z / S;
    int s = blockIdx.z - batch * S;
    const u16* Ahi = batch ? Ahi1 : Ahi0;
    const u16* Alo = batch ? Alo1 : Alo0;
    const u16* Bhi = batch ? Bhi1 : Bhi0;
    const u16* Blo = batch ? Blo1 : Blo0;
    const float* bias = batch ? bias1 : bias0;
    float* C = batch ? C1 : C0;

    constexpr int PARTS = (SPLIT == 3) ? 2 : 1;
    __shared__ u16 smA[2 * PARTS * 8 * 512];
    __shared__ u16 smB[2 * PARTS * 8 * 512];

    int tid = threadIdx.x;
    int w = tid >> 6, L = tid & 63;
    int m15 = L & 15, q = L >> 4;
    int KT = K >> 5;
    int rowTile = blockIdx.y * 8, colTile = blockIdx.x * 8;
    int NIT = (K / S) >> 5;
    int kb0 = s * NIT;
    int aw = w & 1, bw = w >> 1;

    f32x4 acc[4][4];
#pragma unroll
    for (int i = 0; i < 4; ++i)
#pragma unroll
        for (int j = 0; j < 4; ++j) acc[i][j] = (f32x4){0.f, 0.f, 0.f, 0.f};

    auto stage = [&](int buf, int kb) {
#pragma unroll
        for (int rl = 0; rl < 2; ++rl) {
            int rb = 2 * w + rl;
            glds16(Ahi + ((size_t)(rowTile + rb) * KT + kb) * 512 + (size_t)L * 8,
                   &smA[((buf * PARTS + 0) * 8 + rb) * 512]);
            glds16(Bhi + ((size_t)(colTile + rb) * KT + kb) * 512 + (size_t)L * 8,
                   &smB[((buf * PARTS + 0) * 8 + rb) * 512]);
            if constexpr (SPLIT == 3) {
                glds16(Alo + ((size_t)(rowTile + rb) * KT + kb) * 512 + (size_t)L * 8,
                       &smA[((buf * PARTS + 1) * 8 + rb) * 512]);
                glds16(Blo + ((size_t)(colTile + rb) * KT + kb) * 512 + (size_t)L * 8,
                       &smB[((buf * PARTS + 1) * 8 + rb) * 512]);
            }
        }
    };

    stage(0, kb0);
    for (int it = 0; it < NIT; ++it) {
        __syncthreads();
        if (it + 1 < NIT) stage((it + 1) & 1, kb0 + it + 1);
        int buf = it & 1;
        short8 ah[4], bh[4];
#pragma unroll
        for (int i = 0; i < 4; ++i) {
            ah[i] = *(const short8*)&smA[((buf * PARTS + 0) * 8 + aw * 4 + i) * 512 + L * 8];
            bh[i] = *(const short8*)&smB[((buf * PARTS + 0) * 8 + bw * 4 + i) * 512 + L * 8];
        }
        if constexpr (SPLIT == 3) {
            short8 al[4], bl[4];
#pragma unroll
            for (int i = 0; i < 4; ++i) {
                al[i] = *(const short8*)&smA[((buf * PARTS + 1) * 8 + aw * 4 + i) * 512 + L * 8];
                bl[i] = *(const short8*)&smB[((buf * PARTS + 1) * 8 + bw * 4 + i) * 512 + L * 8];
            }
#pragma unroll
            for (int i = 0; i < 4; ++i)
#pragma unroll
                for (int j = 0; j < 4; ++j) {
                    acc[i][j] = __builtin_amdgcn_mfma_f32_16x16x32_bf16(ah[i], bl[j], acc[i][j], 0, 0, 0);
                    acc[i][j] = __builtin_amdgcn_mfma_f32_16x16x32_bf16(al[i], bh[j], acc[i][j], 0, 0, 0);
                    acc[i][j] = __builtin_amdgcn_mfma_f32_16x16x32_bf16(ah[i], bh[j], acc[i][j], 0, 0, 0);
                }
        } else {
#pragma unroll
            for (int i = 0; i < 4; ++i)
#pragma unroll
                for (int j = 0; j < 4; ++j)
                    acc[i][j] = __builtin_amdgcn_mfma_f32_16x16x32_bf16(ah[i], bh[j], acc[i][j], 0, 0, 0);
        }
    }

    if constexpr (FINAL == 0) C += (size_t)s * M * N;
#pragma unroll
    for (int i = 0; i < 4; ++i) {
        int row = rowTile * 16 + aw * 64 + i * 16 + q * 4;
#pragma unroll
        for (int j = 0; j < 4; ++j) {
            int col = colTile * 16 + bw * 64 + j * 16 + m15;
            float bv = (FINAL && bias) ? bias[col] : 0.f;
#pragma unroll
            for (int r = 0; r < 4; ++r) {
                float v = acc[i][j][r];
                if constexpr (FINAL) {
                    v += bv;
                    if (ACT == 1) v = fmaxf(v, 0.f);
                    if (ACT == 2) v = 1.f / (1.f + expf(-v));
                }
                C[(size_t)(row + r) * N + col] = v;
            }
        }
    }
}

// ---------------------------------------------------------------------------
// K3b: split-K reduce -> f32 [M][N] with bias/act. Dual pointer sets via blockIdx.y.
// ---------------------------------------------------------------------------
template<int ACT>
__global__ void reduce_f32(const float* __restrict__ P0, const float* __restrict__ bias0,
                           float* __restrict__ C0,
                           const float* __restrict__ P1, const float* __restrict__ bias1,
                           float* __restrict__ C1, int S, int M, int N) {
    const float* P = blockIdx.y ? P1 : P0;
    const float* bias = blockIdx.y ? bias1 : bias0;
    float* C = blockIdx.y ? C1 : C0;
    int idx = blockIdx.x * 256 + threadIdx.x;
    int mn4 = (M * N) >> 2;
    if (idx >= mn4) return;
    f32x4 a = ((const f32x4*)P)[idx];
    for (int s = 1; s < S; ++s) a += ((const f32x4*)P)[(size_t)s * mn4 + idx];
    int col = (idx % (N >> 2)) * 4;
    f32x4 o;
#pragma unroll
    for (int j = 0; j < 4; ++j) {
        float v = a[j] + (bias ? bias[col + j] : 0.f);
        if (ACT == 1) v = fmaxf(v, 0.f);
        if (ACT == 2) v = 1.f / (1.f + expf(-v));
        o[j] = v;
    }
    ((f32x4*)C)[idx] = o;
}

// ---------------------------------------------------------------------------
// K3c: split-K reduce + relu + bias -> split-bf16 TILED (MLP1 hid, M=128, N=HIDN)
// ---------------------------------------------------------------------------
__global__ void reduce_hid(const float* __restrict__ P0, const float* __restrict__ b0,
                           u16* __restrict__ hi0, u16* __restrict__ lo0,
                           const float* __restrict__ P1, const float* __restrict__ b1,
                           u16* __restrict__ hi1, u16* __restrict__ lo1, int S) {
    const float* P = blockIdx.y ? P1 : P0;
    const float* bias = blockIdx.y ? b1 : b0;
    u16* hi = blockIdx.y ? hi1 : hi0;
    u16* lo = blockIdx.y ? lo1 : lo0;
    int idx = blockIdx.x * 256 + threadIdx.x;       // 128*2048/8 = 32768
    int col = (idx & 255) * 8, rowi = idx >> 8;
    size_t base = ((size_t)rowi * HIDN + col) >> 2;
    f32x4 a0 = ((const f32x4*)P)[base], a1 = ((const f32x4*)P)[base + 1];
    for (int s = 1; s < S; ++s) {
        size_t sb = (size_t)s * (128 * HIDN / 4) + base;
        a0 += ((const f32x4*)P)[sb];
        a1 += ((const f32x4*)P)[sb + 1];
    }
    u16x8 h, l;
#pragma unroll
    for (int j = 0; j < 8; ++j) {
        float v = (j < 4 ? a0[j] : a1[j - 4]) + bias[col + j];
        v = fmaxf(v, 0.f);
        u16 hh = f2bf(v);
        h[j] = hh;
        l[j] = f2bf(v - bf2f(hh));
    }
    size_t ob = tiled_off(rowi, col, HIDN);
    *(u16x8*)&hi[ob] = h;
    *(u16x8*)&lo[ob] = l;
}

// ---------------------------------------------------------------------------
// K5: build compress-MLP inputs -> split-bf16 TILED (K=CDIM)
// ---------------------------------------------------------------------------
__global__ void build_cmlp_in(const float* __restrict__ qkv, const float* __restrict__ k_pos,
                              const float* __restrict__ v_pos,
                              u16* __restrict__ ckhi, u16* __restrict__ cklo,
                              u16* __restrict__ cvhi, u16* __restrict__ cvlo) {
    int idx = blockIdx.x * 256 + threadIdx.x;   // 128 * 256 = 32768
    int k = (idx & 255) * 8;
    int r = idx >> 8;                           // 0..127 = h*W + w
    int p = k >> 6, d = k & 63;
    int h = r >> 5, wb = r & 31;
    int nn = wb * BSZ + p;
    const float* kq = qkv + (size_t)nn * QKVD + (HEADS + h) * DH + d;
    const float* vq = qkv + (size_t)nn * QKVD + (HEADS + KVH + h) * DH + d;
    const float* kp = k_pos + (size_t)(h * BSZ + p) * DH + d;
    const float* vp = v_pos + (size_t)(h * BSZ + p) * DH + d;
    u16x8 kh, kl, vh, vl;
#pragma unroll
    for (int j = 0; j < 8; ++j) {
        float kv = kq[j] + kp[j];
        float vv = vq[j] + vp[j];
        u16 a = f2bf(kv), b = f2bf(vv);
        kh[j] = a; kl[j] = f2bf(kv - bf2f(a));
        vh[j] = b; vl[j] = f2bf(vv - bf2f(b));
    }
    size_t ob = tiled_off(r, k, CDIM);
    *(u16x8*)&ckhi[ob] = kh; *(u16x8*)&cklo[ob] = kl;
    *(u16x8*)&cvhi[ob] = vh; *(u16x8*)&cvlo[ob] = vl;
}

// ---------------------------------------------------------------------------
// K6: assemble ck/cv = concat(mem_kv, mlp_out[128-padded rows]) : [KVH][33][DH]
// ---------------------------------------------------------------------------
__global__ void assemble_ckcv(const float* __restrict__ mem_kv, const float* __restrict__ ckp,
                              const float* __restrict__ cvp,
                              float* __restrict__ ck, float* __restrict__ cv) {
    int idx = blockIdx.x * 256 + threadIdx.x;   // 4*33*64 = 8448
    if (idx >= KVH * 33 * DH) return;
    int d = idx & 63;
    int j = (idx >> 6) % 33;
    int h = idx / (33 * 64);
    if (j == 0) {
        ck[idx] = mem_kv[(0 * KVH + h) * DH + d];
        cv[idx] = mem_kv[(1 * KVH + h) * DH + d];
    } else {
        ck[idx] = ckp[(size_t)(h * WBLK + (j - 1)) * 128 + d];
        cv[idx] = cvp[(size_t)(h * WBLK + (j - 1)) * 128 + d];
    }
}

// ---------------------------------------------------------------------------
// K7: interleaved rotary for q (16 heads) and k (4 heads)
// ---------------------------------------------------------------------------
__global__ void rotary_kernel(const float* __restrict__ qkv,
                              float* __restrict__ qr, float* __restrict__ kr) {
    int idx = blockIdx.x * 256 + threadIdx.x;   // 20*1024*32 = 655360
    int i = idx & 31;
    int n = (idx >> 5) & 1023;
    int hd = idx >> 15;
    if (hd >= HEADS + KVH) return;
    float inv = powf(10000.f, -(float)i / 32.f);
    float fr = (float)n * inv;
    float c = cosf(fr), s = sinf(fr);
    const float* src; float* dst;
    if (hd < HEADS) { src = qkv + (size_t)n * QKVD + hd * DH;          dst = qr + ((size_t)hd * NTOK + n) * DH; }
    else { int h = hd - HEADS;
           src = qkv + (size_t)n * QKVD + (HEADS + h) * DH;            dst = kr + ((size_t)h * NTOK + n) * DH; }
    float x0 = src[2 * i], x1 = src[2 * i + 1];
    dst[2 * i]     = x0 * c - x1 * s;
    dst[2 * i + 1] = x1 * c + x0 * s;
}

// ---------------------------------------------------------------------------
// K8: compressed attention + importance softmax + top-k selection.
// ---------------------------------------------------------------------------
__global__ void cattn_kernel(const float* __restrict__ qkv, const float* __restrict__ ck,
                             const float* __restrict__ cv, float* __restrict__ c_out,
                             int* __restrict__ sel, int* __restrict__ selmask) {
    int n = blockIdx.x, h = blockIdx.y;
    int lane = threadIdx.x;          // 0..63, single wave
    __shared__ float cks[33 * 65];
    __shared__ float cvs[33 * 65];
    __shared__ float qs[4 * 64];
    __shared__ float sims[4 * 33];
    __shared__ float attn_s[64];

    for (int t4 = lane; t4 < 33 * 16; t4 += 64) {
        int j = t4 >> 4, d4 = (t4 & 15) * 4;
        float4 a = *(const float4*)&ck[(size_t)h * 33 * 64 + j * 64 + d4];
        float4 b = *(const float4*)&cv[(size_t)h * 33 * 64 + j * 64 + d4];
        cks[j * 65 + d4 + 0] = a.x; cks[j * 65 + d4 + 1] = a.y;
        cks[j * 65 + d4 + 2] = a.z; cks[j * 65 + d4 + 3] = a.w;
        cvs[j * 65 + d4 + 0] = b.x; cvs[j * 65 + d4 + 1] = b.y;
        cvs[j * 65 + d4 + 2] = b.z; cvs[j * 65 + d4 + 3] = b.w;
    }
#pragma unroll
    for (int g = 0; g < GQ; ++g)
        qs[g * 64 + lane] = qkv[(size_t)n * QKVD + (h * GQ + g) * DH + lane];
    __syncthreads();

    for (int g = 0; g < GQ; ++g) {
        float s = NEGINF;
        if (lane < 33) {
            float acc = 0.f;
#pragma unroll
            for (int d = 0; d < 64; ++d) acc = fmaf(qs[g * 64 + d], cks[lane * 65 + d], acc);
            s = acc * SCALE;
            sims[g * 33 + lane] = s;
        }
        float m = s;
        for (int off = 32; off; off >>= 1) m = fmaxf(m, __shfl_xor(m, off));
        float e = (lane < 33) ? expf(s - m) : 0.f;
        float sum = e;
        for (int off = 32; off; off >>= 1) sum += __shfl_xor(sum, off);
        attn_s[lane] = (lane < 33) ? e / sum : 0.f;
        __syncthreads();
        float acc2 = 0.f;
#pragma unroll
        for (int j = 0; j < 33; ++j) acc2 = fmaf(attn_s[j], cvs[j * 65 + lane], acc2);
        c_out[(((size_t)(h * GQ + g)) * NTOK + n) * DH + lane] = acc2;
        __syncthreads();
    }

    float ival = NEGINF;
    if (lane < 32)
        ival = 0.25f * (sims[0 * 33 + 1 + lane] + sims[1 * 33 + 1 + lane] +
                        sims[2 * 33 + 1 + lane] + sims[3 * 33 + 1 + lane]);
    float m = ival;
    for (int off = 32; off; off >>= 1) m = fmaxf(m, __shfl_xor(m, off));
    float e = (lane < 32) ? expf(ival - m) : 0.f;
    float sum = e;
    for (int off = 32; off; off >>= 1) sum += __shfl_xor(sum, off);
    float p = (lane < 32) ? e / sum : NEGINF;

    float v = p;
    int base = (h * NTOK + n) * 9;
    for (int t = 0; t < NSEL; ++t) {
        float bv = v; int bi = lane;
        for (int off = 32; off; off >>= 1) {
            float ov = __shfl_xor(bv, off);
            int   oi = __shfl_xor(bi, off);
            if (ov > bv || (ov == bv && oi < bi)) { bv = ov; bi = oi; }
        }
        if (lane == 0) { sel[base + t] = bi; selmask[base + t] = (bv > 1e-10f) ? 1 : 0; }
        if (lane == bi) v = NEGINF;
    }
    if (lane == 0) { sel[base + NSEL] = n >> 5; selmask[base + NSEL] = 1; }
}

// ---------------------------------------------------------------------------
// K9: fine (selected-block) attention. float4 staging.
// ---------------------------------------------------------------------------
__global__ void fattn_kernel(const float* __restrict__ qr, const float* __restrict__ kr,
                             const float* __restrict__ qkv, const int* __restrict__ sel,
                             const int* __restrict__ selmask, float* __restrict__ f_out) {
    int n = blockIdx.x, h = blockIdx.y;
    int tid = threadIdx.x;           // 256
    __shared__ float qs[4 * 64];
    __shared__ float kvs[32 * 65];
    __shared__ float sims[4 * 288];
    __shared__ int sel_s[9], msk_s[9];

    if (tid < 9) {
        sel_s[tid] = sel[(h * NTOK + n) * 9 + tid];
        msk_s[tid] = selmask[(h * NTOK + n) * 9 + tid];
    }
    qs[tid] = qr[(((size_t)(h * GQ + (tid >> 6))) * NTOK + n) * DH + (tid & 63)];
    __syncthreads();

    for (int b = 0; b < 9; ++b) {
        int blk = sel_s[b];
        for (int t4 = tid; t4 < BSZ * DH / 4; t4 += 256) {
            int j = t4 >> 4, d4 = (t4 & 15) * 4;
            float4 v = *(const float4*)&kr[((size_t)h * NTOK + blk * BSZ + j) * DH + d4];
            kvs[j * 65 + d4 + 0] = v.x; kvs[j * 65 + d4 + 1] = v.y;
            kvs[j * 65 + d4 + 2] = v.z; kvs[j * 65 + d4 + 3] = v.w;
        }
        __syncthreads();
        if (tid < 128) {
            int g = tid >> 5, j = tid & 31;
            float s;
            if (msk_s[b]) {
                float acc = 0.f;
#pragma unroll
                for (int d = 0; d < 64; ++d) acc = fmaf(qs[g * 64 + d], kvs[j * 65 + d], acc);
                s = acc * SCALE;
            } else s = -3.402823466e+38f;
            sims[g * 288 + b * 32 + j] = s;
        }
        __syncthreads();
    }

    {
        int g = tid >> 6, lane = tid & 63;
        float m = NEGINF;
        for (int t = lane; t < 288; t += 64) m = fmaxf(m, sims[g * 288 + t]);
        for (int off = 32; off; off >>= 1) m = fmaxf(m, __shfl_xor(m, off));
        float ev[5];
        int cnt = 0;
        float sum = 0.f;
        for (int t = lane; t < 288; t += 64) { float ee = expf(sims[g * 288 + t] - m); ev[cnt++] = ee; sum += ee; }
        for (int off = 32; off; off >>= 1) sum += __shfl_xor(sum, off);
        float inv = 1.f / sum;
        cnt = 0;
        for (int t = lane; t < 288; t += 64) sims[g * 288 + t] = ev[cnt++] * inv;
    }
    __syncthreads();

    int g = tid >> 6, d = tid & 63;
    float acc = 0.f;
    for (int b = 0; b < 9; ++b) {
        int blk = sel_s[b];
        for (int t4 = tid; t4 < BSZ * DH / 4; t4 += 256) {
            int j = t4 >> 4, d4 = (t4 & 15) * 4;
            float4 v = *(const float4*)&qkv[((size_t)(blk * BSZ + j)) * QKVD + (HEADS + KVH + h) * DH + d4];
            kvs[j * 65 + d4 + 0] = v.x; kvs[j * 65 + d4 + 1] = v.y;
            kvs[j * 65 + d4 + 2] = v.z; kvs[j * 65 + d4 + 3] = v.w;
        }
        __syncthreads();
#pragma unroll
        for (int j = 0; j < 32; ++j) acc = fmaf(sims[g * 288 + b * 32 + j], kvs[j * 65 + d], acc);
        __syncthreads();
    }
    f_out[(((size_t)(h * GQ + g)) * NTOK + n) * DH + d] = acc;
}

// ---------------------------------------------------------------------------
// K10: gated mix -> split-bf16 TILED (K=DDIM). gates f32 [N][128] padded.
// ---------------------------------------------------------------------------
__global__ void mix_kernel(const float* __restrict__ gates, const float* __restrict__ c_out,
                           const float* __restrict__ f_out,
                           u16* __restrict__ mixhi, u16* __restrict__ mixlo) {
    int idx = blockIdx.x * 256 + threadIdx.x;   // 1024*1024/8 = 131072
    int col = (idx & 127) * 8;
    int n = idx >> 7;
    int hd = col >> 6, d = col & 63;
    float g0 = gates[(size_t)n * 128 + hd * 2];
    float g1 = gates[(size_t)n * 128 + hd * 2 + 1];
    size_t hoff = (((size_t)hd) * NTOK + n) * DH + d;
    u16x8 h, l;
#pragma unroll
    for (int j = 0; j < 8; ++j) {
        float v = g0 * c_out[hoff + j] + g1 * f_out[hoff + j];
        u16 hh = f2bf(v);
        h[j] = hh;
        l[j] = f2bf(v - bf2f(hh));
    }
    size_t ob = tiled_off(n, col, DDIM);
    *(u16x8*)&mixhi[ob] = h;
    *(u16x8*)&mixlo[ob] = l;
}

// ---------------------------------------------------------------------------
extern "C" void kernel_launch(void* const* d_in, const int* in_sizes, int n_in,
                              void* d_out, int out_size, void* d_ws, size_t ws_size,
                              hipStream_t stream) {
    const float* inp    = (const float*)d_in[0];
    const float* g_norm = (const float*)d_in[1];
    const float* w_qkv  = (const float*)d_in[2];
    const float* mem_kv = (const float*)d_in[3];
    const float* k_pos  = (const float*)d_in[4];
    const float* v_pos  = (const float*)d_in[5];
    const float* k_w1   = (const float*)d_in[6];
    const float* k_b1   = (const float*)d_in[7];
    const float* k_w2   = (const float*)d_in[8];
    const float* k_b2   = (const float*)d_in[9];
    const float* v_w1   = (const float*)d_in[10];
    const float* v_b1   = (const float*)d_in[11];
    const float* v_w2   = (const float*)d_in[12];
    const float* v_b2   = (const float*)d_in[13];
    const float* gate_w = (const float*)d_in[14];
    const float* gate_b = (const float*)d_in[15];
    const float* w_out  = (const float*)d_in[16];
    float* out = (float*)d_out;

    char* wsb = (char*)d_ws;
    size_t off = 0;
    auto alloc = [&](size_t bytes) -> void* {
        void* p = wsb + off;
        off = (off + bytes + 255) & ~(size_t)255;
        return p;
    };
    u16*   xhi    = (u16*)  alloc((size_t)NTOK * DDIM * 2);
    u16*   xlo    = (u16*)  alloc((size_t)NTOK * DDIM * 2);
    float* qkvb   = (float*)alloc((size_t)NTOK * QKVD * 4);
    u16*   wqThi  = (u16*)  alloc((size_t)QKVD * DDIM * 2);
    u16*   wqTlo  = (u16*)  alloc((size_t)QKVD * DDIM * 2);
    u16*   kw1Thi = (u16*)  alloc((size_t)HIDN * CDIM * 2);
    u16*   kw1Tlo = (u16*)  alloc((size_t)HIDN * CDIM * 2);
    u16*   vw1Thi = (u16*)  alloc((size_t)HIDN * CDIM * 2);
    u16*   vw1Tlo = (u16*)  alloc((size_t)HIDN * CDIM * 2);
    u16*   woThi  = (u16*)  alloc((size_t)DDIM * DDIM * 2);
    u16*   gwThi  = (u16*)  alloc((size_t)128 * DDIM * 2);
    u16*   gwTlo  = (u16*)  alloc((size_t)128 * DDIM * 2);
    float* gbp    = (float*)alloc(128 * 4);
    u16*   kw2Thi = (u16*)  alloc((size_t)128 * HIDN * 2);
    u16*   kw2Tlo = (u16*)  alloc((size_t)128 * HIDN * 2);
    float* kb2p   = (float*)alloc(128 * 4);
    u16*   vw2Thi = (u16*)  alloc((size_t)128 * HIDN * 2);
    u16*   vw2Tlo = (u16*)  alloc((size_t)128 * HIDN * 2);
    float* vb2p   = (float*)alloc(128 * 4);
    u16*   cinkhi = (u16*)  alloc((size_t)128 * CDIM * 2);
    u16*   cinklo = (u16*)  alloc((size_t)128 * CDIM * 2);
    u16*   cinvhi = (u16*)  alloc((size_t)128 * CDIM * 2);
    u16*   cinvlo = (u16*)  alloc((size_t)128 * CDIM * 2);
    u16*   hidkhi = (u16*)  alloc((size_t)128 * HIDN * 2);
    u16*   hidklo = (u16*)  alloc((size_t)128 * HIDN * 2);
    u16*   hidvhi = (u16*)  alloc((size_t)128 * HIDN * 2);
    u16*   hidvlo = (u16*)  alloc((size_t)128 * HIDN * 2);
    float* Pg     = (float*)alloc((size_t)8 * NTOK * 128 * 4);
    float* Pm1k   = (float*)alloc((size_t)4 * 128 * HIDN * 4);
    float* Pm1v   = (float*)alloc((size_t)4 * 128 * HIDN * 4);
    float* Pm2k   = (float*)alloc((size_t)8 * 128 * 128 * 4);
    float* Pm2v   = (float*)alloc((size_t)8 * 128 * 128 * 4);
    float* ckp    = (float*)alloc((size_t)128 * 128 * 4);
    float* cvp    = (float*)alloc((size_t)128 * 128 * 4);
    float* ck     = (float*)alloc((size_t)KVH * 33 * DH * 4);
    float* cv     = (float*)alloc((size_t)KVH * 33 * DH * 4);
    float* qr     = (float*)alloc((size_t)HEADS * NTOK * DH * 4);
    float* kr     = (float*)alloc((size_t)KVH * NTOK * DH * 4);
    float* c_out  = (float*)alloc((size_t)HEADS * NTOK * DH * 4);
    float* f_out  = (float*)alloc((size_t)HEADS * NTOK * DH * 4);
    float* gates  = (float*)alloc((size_t)NTOK * 128 * 4);
    int*   sel    = (int*)  alloc((size_t)KVH * NTOK * 9 * 4);
    int*   selmask= (int*)  alloc((size_t)KVH * NTOK * 9 * 4);
    u16*   mixhi  = (u16*)  alloc((size_t)NTOK * DDIM * 2);
    u16*   mixlo  = (u16*)  alloc((size_t)NTOK * DDIM * 2);

    // weight prep (tiled layouts)
    transpose_split<<<dim3(QKVD / 64, DDIM / 64), 256, 0, stream>>>(w_qkv, wqThi, wqTlo, DDIM, QKVD);
    transpose_split<<<dim3(HIDN / 64, CDIM / 64), 256, 0, stream>>>(k_w1, kw1Thi, kw1Tlo, CDIM, HIDN);
    transpose_split<<<dim3(HIDN / 64, CDIM / 64), 256, 0, stream>>>(v_w1, vw1Thi, vw1Tlo, CDIM, HIDN);
    transpose_split<<<dim3(DDIM / 64, DDIM / 64), 256, 0, stream>>>(w_out, woThi, nullptr, DDIM, DDIM);
    pad_small_tiled<<<(128 * DDIM / 8) / 256, 256, 0, stream>>>(gate_w, gate_b, gwThi, gwTlo, gbp, DDIM, 32, 10);
    pad_small_tiled<<<(128 * HIDN / 8) / 256, 256, 0, stream>>>(k_w2, k_b2, kw2Thi, kw2Tlo, kb2p, HIDN, 64, 11);
    pad_small_tiled<<<(128 * HIDN / 8) / 256, 256, 0, stream>>>(v_w2, v_b2, vw2Thi, vw2Tlo, vb2p, HIDN, 64, 11);

    // 1. RMSNorm -> tiled split-bf16 x
    rmsnorm_kernel<<<NTOK / 2, 256, 0, stream>>>(inp, g_norm, xhi, xlo);
    // 2. qkv = x @ w_qkv (final f32)
    gemm_tiled<3, 0, 1><<<dim3(QKVD / 128, NTOK / 128, 1), 256, 0, stream>>>(
        xhi, xlo, wqThi, wqTlo, nullptr, qkvb,
        xhi, xlo, wqThi, wqTlo, nullptr, qkvb, NTOK, QKVD, DDIM, 1);
    // 3. gates (split-K 8 + sigmoid reduce)
    gemm_tiled<3, 0, 0><<<dim3(1, NTOK / 128, 8), 256, 0, stream>>>(
        xhi, xlo, gwThi, gwTlo, nullptr, Pg,
        xhi, xlo, gwThi, gwTlo, nullptr, Pg, NTOK, 128, DDIM, 8);
    reduce_f32<2><<<dim3(128, 1), 256, 0, stream>>>(Pg, gbp, gates, Pg, gbp, gates, 8, NTOK, 128);
    // 4. compress-MLP inputs (tiled)
    build_cmlp_in<<<128, 256, 0, stream>>>(qkvb, k_pos, v_pos, cinkhi, cinklo, cinvhi, cinvlo);
    // 5. MLP1 (split-K 4, k&v batched; relu+bias+split-tile in reduce)
    gemm_tiled<3, 0, 0><<<dim3(HIDN / 128, 1, 8), 256, 0, stream>>>(
        cinkhi, cinklo, kw1Thi, kw1Tlo, nullptr, Pm1k,
        cinvhi, cinvlo, vw1Thi, vw1Tlo, nullptr, Pm1v, 128, HIDN, CDIM, 4);
    reduce_hid<<<dim3(128, 2), 256, 0, stream>>>(Pm1k, k_b1, hidkhi, hidklo,
                                                 Pm1v, v_b1, hidvhi, hidvlo, 4);
    // 6. MLP2 (split-K 8, k&v batched)
    gemm_tiled<3, 0, 0><<<dim3(1, 1, 16), 256, 0, stream>>>(
        hidkhi, hidklo, kw2Thi, kw2Tlo, nullptr, Pm2k,
        hidvhi, hidvlo, vw2Thi, vw2Tlo, nullptr, Pm2v, 128, 128, HIDN, 8);
    reduce_f32<0><<<dim3(16, 2), 256, 0, stream>>>(Pm2k, kb2p, ckp, Pm2v, vb2p, cvp, 8, 128, 128);
    // 7. concat mem_kv
    assemble_ckcv<<<(KVH * 33 * DH + 255) / 256, 256, 0, stream>>>(mem_kv, ckp, cvp, ck, cv);
    // 8. rotary
    rotary_kernel<<<((HEADS + KVH) * NTOK * 32) / 256, 256, 0, stream>>>(qkvb, qr, kr);
    // 9. compressed attention + selection
    cattn_kernel<<<dim3(NTOK, KVH), 64, 0, stream>>>(qkvb, ck, cv, c_out, sel, selmask);
    // 10. fine attention
    fattn_kernel<<<dim3(NTOK, KVH), 256, 0, stream>>>(qr, kr, qkvb, sel, selmask, f_out);
    // 11. gated mix -> tiled split-bf16
    mix_kernel<<<(NTOK * DDIM / 8) / 256, 256, 0, stream>>>(gates, c_out, f_out, mixhi, mixlo);
    // 12. output projection (bf16, final)
    gemm_tiled<1, 0, 1><<<dim3(DDIM / 128, NTOK / 128, 1), 256, 0, stream>>>(
        mixhi, mixhi, woThi, woThi, nullptr, out,
        mixhi, mixhi, woThi, woThi, nullptr, out, NTOK, DDIM, DDIM, 1);
}

// Round 5
// 379.813 us; speedup vs baseline: 1.6786x; 1.0215x over previous
//
#include <hip/hip_runtime.h>
#include <math.h>

// ---- fixed problem sizes ----
#define NTOK 1024
#define DDIM 1024
#define HEADS 16
#define KVH 4
#define DH 64
#define BSZ 32
#define NSEL 8
#define WBLK 32            // NTOK / BSZ
#define GQ 4               // HEADS / KVH
#define CDIM 2048          // BSZ*DH
#define HIDN 2048
#define QKVD 1536          // (HEADS + 2*KVH)*DH
#define SCALE 0.125f       // DH^-0.5
#define NEGINF (-__builtin_inff())

typedef unsigned short u16;
typedef u16   u16x8  __attribute__((ext_vector_type(8)));
typedef short short8 __attribute__((ext_vector_type(8)));
typedef float f32x4  __attribute__((ext_vector_type(4)));

__device__ __forceinline__ u16 f2bf(float f) {
    unsigned u = __float_as_uint(f);
    return (u16)((u + 0x7fffu + ((u >> 16) & 1u)) >> 16);
}
__device__ __forceinline__ float bf2f(u16 h) { return __uint_as_float(((unsigned)h) << 16); }

__device__ __forceinline__ void glds16(const void* g, void* l) {
    __builtin_amdgcn_global_load_lds(
        (const __attribute__((address_space(1))) unsigned int*)g,
        (__attribute__((address_space(3))) unsigned int*)l, 16, 0, 0);
}

// element offset (in u16) of the 8-element lane-slot for (row, k..k+7) in the
// MFMA-fragment-tiled layout: 16-row x 32-k tiles, 1KB each, contiguous.
__device__ __forceinline__ size_t tiled_off(int row, int k, int K) {
    return ((size_t)((row >> 4) * (K >> 5) + (k >> 5)) * 64 +
            ((row & 15) | (((k >> 3) & 3) << 4))) * 8;
}

// ---------------------------------------------------------------------------
// K1: RMSNorm -> split-bf16 x in TILED layout (K=DDIM). 2 rows per 256-thr block.
// ---------------------------------------------------------------------------
__global__ void rmsnorm_kernel(const float* __restrict__ inp, const float* __restrict__ g,
                               u16* __restrict__ xhi, u16* __restrict__ xlo) {
    int t = threadIdx.x;
    int half = t >> 7, tid = t & 127;
    int n = blockIdx.x * 2 + half;
    const float4* row = (const float4*)(inp + (size_t)n * DDIM);
    float4 v0 = row[tid * 2], v1 = row[tid * 2 + 1];
    float ss = v0.x*v0.x + v0.y*v0.y + v0.z*v0.z + v0.w*v0.w
             + v1.x*v1.x + v1.y*v1.y + v1.z*v1.z + v1.w*v1.w;
    for (int off = 32; off; off >>= 1) ss += __shfl_down(ss, off);
    __shared__ float red[4];
    if ((t & 63) == 0) red[t >> 6] = ss;
    __syncthreads();
    float tot = red[half * 2] + red[half * 2 + 1];
    float r = 1.f / sqrtf(tot * (1.f / DDIM) + 1e-6f);
    const float4* gp = (const float4*)g;
    float4 g0 = gp[tid * 2], g1 = gp[tid * 2 + 1];
    float o[8] = { v0.x*r*g0.x, v0.y*r*g0.y, v0.z*r*g0.z, v0.w*r*g0.w,
                   v1.x*r*g1.x, v1.y*r*g1.y, v1.z*r*g1.z, v1.w*r*g1.w };
    u16x8 h, l;
#pragma unroll
    for (int i = 0; i < 8; ++i) {
        u16 hh = f2bf(o[i]);
        h[i] = hh;
        l[i] = f2bf(o[i] - bf2f(hh));
    }
    size_t ob = tiled_off(n, tid * 8, DDIM);
    *(u16x8*)&xhi[ob] = h;
    *(u16x8*)&xlo[ob] = l;
}

// ---------------------------------------------------------------------------
// K2: weight transpose + split: W[K][N] f32 -> tiled Bt[N][K] bf16 hi/lo
// ---------------------------------------------------------------------------
__global__ void transpose_split(const float* __restrict__ W, u16* __restrict__ Thi,
                                u16* __restrict__ Tlo, int K, int N) {
    __shared__ float tile[64][65];
    int k0 = blockIdx.y * 64, n0 = blockIdx.x * 64;
    int t = threadIdx.x;
    int r = t >> 4, c4 = (t & 15) * 4;
#pragma unroll
    for (int p = 0; p < 4; ++p) {
        float4 v = *(const float4*)&W[(size_t)(k0 + r + p * 16) * N + n0 + c4];
        tile[r + p * 16][c4 + 0] = v.x;
        tile[r + p * 16][c4 + 1] = v.y;
        tile[r + p * 16][c4 + 2] = v.z;
        tile[r + p * 16][c4 + 3] = v.w;
    }
    __syncthreads();
    int n = t >> 2, ks = (t & 3) * 16;
#pragma unroll
    for (int c = 0; c < 2; ++c) {
        u16x8 h, l;
#pragma unroll
        for (int j = 0; j < 8; ++j) {
            float v = tile[ks + c * 8 + j][n];
            u16 hh = f2bf(v);
            h[j] = hh;
            l[j] = f2bf(v - bf2f(hh));
        }
        size_t ob = tiled_off(n0 + n, k0 + ks + c * 8, K);
        *(u16x8*)&Thi[ob] = h;
        if (Tlo) *(u16x8*)&Tlo[ob] = l;
    }
}

// ---------------------------------------------------------------------------
// K2b: pad small weights [K][Xn] (Xn<=64) -> tiled split-bf16 [128][K] + padded bias
// ---------------------------------------------------------------------------
__global__ void pad_small_tiled(const float* __restrict__ W, const float* __restrict__ b,
                                u16* __restrict__ Thi, u16* __restrict__ Tlo,
                                float* __restrict__ bias_pad, int K, int Xn, int KLOG) {
    int idx = blockIdx.x * 256 + threadIdx.x;   // 128 * K/8
    int k = (idx & ((K >> 3) - 1)) * 8;
    int n = idx >> (KLOG - 3);
    if (n >= 128) return;
    u16x8 h, l;
#pragma unroll
    for (int j = 0; j < 8; ++j) {
        float v = (n < Xn) ? W[(size_t)(k + j) * Xn + n] : 0.f;
        u16 hh = f2bf(v);
        h[j] = hh;
        l[j] = f2bf(v - bf2f(hh));
    }
    size_t ob = tiled_off(n, k, K);
    *(u16x8*)&Thi[ob] = h;
    *(u16x8*)&Tlo[ob] = l;
    if (k == 0) bias_pad[n] = (n < Xn) ? b[n] : 0.f;
}

// ---------------------------------------------------------------------------
// K3: tiled MFMA GEMM with software pipeline + optional split-K.
// ---------------------------------------------------------------------------
template<int SPLIT, int ACT, int FINAL>
__global__ __launch_bounds__(256, 1)
void gemm_tiled(const u16* __restrict__ Ahi0, const u16* __restrict__ Alo0,
                const u16* __restrict__ Bhi0, const u16* __restrict__ Blo0,
                const float* __restrict__ bias0, float* __restrict__ C0,
                const u16* __restrict__ Ahi1, const u16* __restrict__ Alo1,
                const u16* __restrict__ Bhi1, const u16* __restrict__ Blo1,
                const float* __restrict__ bias1, float* __restrict__ C1,
                int M, int N, int K, int S) {
    int batch = blockIdx.z / S;
    int s = blockIdx.z - batch * S;
    const u16* Ahi = batch ? Ahi1 : Ahi0;
    const u16* Alo = batch ? Alo1 : Alo0;
    const u16* Bhi = batch ? Bhi1 : Bhi0;
    const u16* Blo = batch ? Blo1 : Blo0;
    const float* bias = batch ? bias1 : bias0;
    float* C = batch ? C1 : C0;

    constexpr int PARTS = (SPLIT == 3) ? 2 : 1;
    __shared__ u16 smA[2 * PARTS * 8 * 512];
    __shared__ u16 smB[2 * PARTS * 8 * 512];

    int tid = threadIdx.x;
    int w = tid >> 6, L = tid & 63;
    int m15 = L & 15, q = L >> 4;
    int KT = K >> 5;
    int rowTile = blockIdx.y * 8, colTile = blockIdx.x * 8;
    int NIT = (K / S) >> 5;
    int kb0 = s * NIT;
    int aw = w & 1, bw = w >> 1;

    f32x4 acc[4][4];
#pragma unroll
    for (int i = 0; i < 4; ++i)
#pragma unroll
        for (int j = 0; j < 4; ++j) acc[i][j] = (f32x4){0.f, 0.f, 0.f, 0.f};

    auto stage = [&](int buf, int kb) {
#pragma unroll
        for (int rl = 0; rl < 2; ++rl) {
            int rb = 2 * w + rl;
            glds16(Ahi + ((size_t)(rowTile + rb) * KT + kb) * 512 + (size_t)L * 8,
                   &smA[((buf * PARTS + 0) * 8 + rb) * 512]);
            glds16(Bhi + ((size_t)(colTile + rb) * KT + kb) * 512 + (size_t)L * 8,
                   &smB[((buf * PARTS + 0) * 8 + rb) * 512]);
            if constexpr (SPLIT == 3) {
                glds16(Alo + ((size_t)(rowTile + rb) * KT + kb) * 512 + (size_t)L * 8,
                       &smA[((buf * PARTS + 1) * 8 + rb) * 512]);
                glds16(Blo + ((size_t)(colTile + rb) * KT + kb) * 512 + (size_t)L * 8,
                       &smB[((buf * PARTS + 1) * 8 + rb) * 512]);
            }
        }
    };

    stage(0, kb0);
    for (int it = 0; it < NIT; ++it) {
        __syncthreads();
        if (it + 1 < NIT) stage((it + 1) & 1, kb0 + it + 1);
        int buf = it & 1;
        short8 ah[4], bh[4];
#pragma unroll
        for (int i = 0; i < 4; ++i) {
            ah[i] = *(const short8*)&smA[((buf * PARTS + 0) * 8 + aw * 4 + i) * 512 + L * 8];
            bh[i] = *(const short8*)&smB[((buf * PARTS + 0) * 8 + bw * 4 + i) * 512 + L * 8];
        }
        if constexpr (SPLIT == 3) {
            short8 al[4], bl[4];
#pragma unroll
            for (int i = 0; i < 4; ++i) {
                al[i] = *(const short8*)&smA[((buf * PARTS + 1) * 8 + aw * 4 + i) * 512 + L * 8];
                bl[i] = *(const short8*)&smB[((buf * PARTS + 1) * 8 + bw * 4 + i) * 512 + L * 8];
            }
#pragma unroll
            for (int i = 0; i < 4; ++i)
#pragma unroll
                for (int j = 0; j < 4; ++j) {
                    acc[i][j] = __builtin_amdgcn_mfma_f32_16x16x32_bf16(ah[i], bl[j], acc[i][j], 0, 0, 0);
                    acc[i][j] = __builtin_amdgcn_mfma_f32_16x16x32_bf16(al[i], bh[j], acc[i][j], 0, 0, 0);
                    acc[i][j] = __builtin_amdgcn_mfma_f32_16x16x32_bf16(ah[i], bh[j], acc[i][j], 0, 0, 0);
                }
        } else {
#pragma unroll
            for (int i = 0; i < 4; ++i)
#pragma unroll
                for (int j = 0; j < 4; ++j)
                    acc[i][j] = __builtin_amdgcn_mfma_f32_16x16x32_bf16(ah[i], bh[j], acc[i][j], 0, 0, 0);
        }
    }

    if constexpr (FINAL == 0) C += (size_t)s * M * N;
#pragma unroll
    for (int i = 0; i < 4; ++i) {
        int row = rowTile * 16 + aw * 64 + i * 16 + q * 4;
#pragma unroll
        for (int j = 0; j < 4; ++j) {
            int col = colTile * 16 + bw * 64 + j * 16 + m15;
            float bv = (FINAL && bias) ? bias[col] : 0.f;
#pragma unroll
            for (int r = 0; r < 4; ++r) {
                float v = acc[i][j][r];
                if constexpr (FINAL) {
                    v += bv;
                    if (ACT == 1) v = fmaxf(v, 0.f);
                    if (ACT == 2) v = 1.f / (1.f + expf(-v));
                }
                C[(size_t)(row + r) * N + col] = v;
            }
        }
    }
}

// ---------------------------------------------------------------------------
// K3b: split-K reduce -> f32 [M][N] with bias/act. Dual pointer sets via blockIdx.y.
// ---------------------------------------------------------------------------
template<int ACT>
__global__ void reduce_f32(const float* __restrict__ P0, const float* __restrict__ bias0,
                           float* __restrict__ C0,
                           const float* __restrict__ P1, const float* __restrict__ bias1,
                           float* __restrict__ C1, int S, int M, int N) {
    const float* P = blockIdx.y ? P1 : P0;
    const float* bias = blockIdx.y ? bias1 : bias0;
    float* C = blockIdx.y ? C1 : C0;
    int idx = blockIdx.x * 256 + threadIdx.x;
    int mn4 = (M * N) >> 2;
    if (idx >= mn4) return;
    f32x4 a = ((const f32x4*)P)[idx];
    for (int s = 1; s < S; ++s) a += ((const f32x4*)P)[(size_t)s * mn4 + idx];
    int col = (idx % (N >> 2)) * 4;
    f32x4 o;
#pragma unroll
    for (int j = 0; j < 4; ++j) {
        float v = a[j] + (bias ? bias[col + j] : 0.f);
        if (ACT == 1) v = fmaxf(v, 0.f);
        if (ACT == 2) v = 1.f / (1.f + expf(-v));
        o[j] = v;
    }
    ((f32x4*)C)[idx] = o;
}

// ---------------------------------------------------------------------------
// K3c: split-K reduce + relu + bias -> split-bf16 TILED (MLP1 hid, M=128, N=HIDN)
// ---------------------------------------------------------------------------
__global__ void reduce_hid(const float* __restrict__ P0, const float* __restrict__ b0,
                           u16* __restrict__ hi0, u16* __restrict__ lo0,
                           const float* __restrict__ P1, const float* __restrict__ b1,
                           u16* __restrict__ hi1, u16* __restrict__ lo1, int S) {
    const float* P = blockIdx.y ? P1 : P0;
    const float* bias = blockIdx.y ? b1 : b0;
    u16* hi = blockIdx.y ? hi1 : hi0;
    u16* lo = blockIdx.y ? lo1 : lo0;
    int idx = blockIdx.x * 256 + threadIdx.x;       // 128*2048/8 = 32768
    int col = (idx & 255) * 8, rowi = idx >> 8;
    size_t base = ((size_t)rowi * HIDN + col) >> 2;
    f32x4 a0 = ((const f32x4*)P)[base], a1 = ((const f32x4*)P)[base + 1];
    for (int s = 1; s < S; ++s) {
        size_t sb = (size_t)s * (128 * HIDN / 4) + base;
        a0 += ((const f32x4*)P)[sb];
        a1 += ((const f32x4*)P)[sb + 1];
    }
    u16x8 h, l;
#pragma unroll
    for (int j = 0; j < 8; ++j) {
        float v = (j < 4 ? a0[j] : a1[j - 4]) + bias[col + j];
        v = fmaxf(v, 0.f);
        u16 hh = f2bf(v);
        h[j] = hh;
        l[j] = f2bf(v - bf2f(hh));
    }
    size_t ob = tiled_off(rowi, col, HIDN);
    *(u16x8*)&hi[ob] = h;
    *(u16x8*)&lo[ob] = l;
}

// ---------------------------------------------------------------------------
// K5: build compress-MLP inputs -> split-bf16 TILED (K=CDIM)
// ---------------------------------------------------------------------------
__global__ void build_cmlp_in(const float* __restrict__ qkv, const float* __restrict__ k_pos,
                              const float* __restrict__ v_pos,
                              u16* __restrict__ ckhi, u16* __restrict__ cklo,
                              u16* __restrict__ cvhi, u16* __restrict__ cvlo) {
    int idx = blockIdx.x * 256 + threadIdx.x;   // 128 * 256 = 32768
    int k = (idx & 255) * 8;
    int r = idx >> 8;                           // 0..127 = h*W + w
    int p = k >> 6, d = k & 63;
    int h = r >> 5, wb = r & 31;
    int nn = wb * BSZ + p;
    const float* kq = qkv + (size_t)nn * QKVD + (HEADS + h) * DH + d;
    const float* vq = qkv + (size_t)nn * QKVD + (HEADS + KVH + h) * DH + d;
    const float* kp = k_pos + (size_t)(h * BSZ + p) * DH + d;
    const float* vp = v_pos + (size_t)(h * BSZ + p) * DH + d;
    u16x8 kh, kl, vh, vl;
#pragma unroll
    for (int j = 0; j < 8; ++j) {
        float kv = kq[j] + kp[j];
        float vv = vq[j] + vp[j];
        u16 a = f2bf(kv), b = f2bf(vv);
        kh[j] = a; kl[j] = f2bf(kv - bf2f(a));
        vh[j] = b; vl[j] = f2bf(vv - bf2f(b));
    }
    size_t ob = tiled_off(r, k, CDIM);
    *(u16x8*)&ckhi[ob] = kh; *(u16x8*)&cklo[ob] = kl;
    *(u16x8*)&cvhi[ob] = vh; *(u16x8*)&cvlo[ob] = vl;
}

// ---------------------------------------------------------------------------
// K6: assemble ck/cv = concat(mem_kv, mlp_out[128-padded rows]) : [KVH][33][DH]
// ---------------------------------------------------------------------------
__global__ void assemble_ckcv(const float* __restrict__ mem_kv, const float* __restrict__ ckp,
                              const float* __restrict__ cvp,
                              float* __restrict__ ck, float* __restrict__ cv) {
    int idx = blockIdx.x * 256 + threadIdx.x;   // 4*33*64 = 8448
    if (idx >= KVH * 33 * DH) return;
    int d = idx & 63;
    int j = (idx >> 6) % 33;
    int h = idx / (33 * 64);
    if (j == 0) {
        ck[idx] = mem_kv[(0 * KVH + h) * DH + d];
        cv[idx] = mem_kv[(1 * KVH + h) * DH + d];
    } else {
        ck[idx] = ckp[(size_t)(h * WBLK + (j - 1)) * 128 + d];
        cv[idx] = cvp[(size_t)(h * WBLK + (j - 1)) * 128 + d];
    }
}

// ---------------------------------------------------------------------------
// K7: interleaved rotary for q (16 heads), k (4 heads) + packed v copy (4 heads)
// ---------------------------------------------------------------------------
__global__ void rotary_kernel(const float* __restrict__ qkv,
                              float* __restrict__ qr, float* __restrict__ kr,
                              float* __restrict__ vr) {
    int idx = blockIdx.x * 256 + threadIdx.x;   // 24*1024*32 = 786432
    int i = idx & 31;
    int n = (idx >> 5) & 1023;
    int hd = idx >> 15;
    if (hd >= 24) return;
    if (hd >= HEADS + KVH) {       // packed v copy
        int h = hd - (HEADS + KVH);
        const float* src = qkv + (size_t)n * QKVD + (HEADS + KVH + h) * DH;
        float* dst = vr + ((size_t)h * NTOK + n) * DH;
        dst[2 * i] = src[2 * i];
        dst[2 * i + 1] = src[2 * i + 1];
        return;
    }
    float inv = powf(10000.f, -(float)i / 32.f);
    float fr = (float)n * inv;
    float c = cosf(fr), s = sinf(fr);
    const float* src; float* dst;
    if (hd < HEADS) { src = qkv + (size_t)n * QKVD + hd * DH;          dst = qr + ((size_t)hd * NTOK + n) * DH; }
    else { int h = hd - HEADS;
           src = qkv + (size_t)n * QKVD + (HEADS + h) * DH;            dst = kr + ((size_t)h * NTOK + n) * DH; }
    float x0 = src[2 * i], x1 = src[2 * i + 1];
    dst[2 * i]     = x0 * c - x1 * s;
    dst[2 * i + 1] = x1 * c + x0 * s;
}

// ---------------------------------------------------------------------------
// K8: compressed attention + importance + top-k. 4 tokens per 256-thr block,
// one wave per token; ck/cv staged ONCE per block; wave-private softmax/top-k.
// ---------------------------------------------------------------------------
__global__ __launch_bounds__(256)
void cattn_kernel(const float* __restrict__ qkv, const float* __restrict__ ck,
                  const float* __restrict__ cv, float* __restrict__ c_out,
                  int* __restrict__ sel, int* __restrict__ selmask) {
    int h = blockIdx.y;
    int tid = threadIdx.x;
    int w = tid >> 6, lane = tid & 63;
    int grp = lane >> 4, sub = lane & 15;
    int n = blockIdx.x * 4 + w;
    __shared__ float cks[33 * 68];
    __shared__ float cvs[33 * 68];
    __shared__ float sims[16 * 36];      // [w*4+g][j]

    for (int t4 = tid; t4 < 1056; t4 += 256) {
        int half = (t4 >= 528) ? 1 : 0;
        int u = t4 - half * 528;
        int j = u >> 4, d4 = (u & 15) * 4;
        const float* src = (half ? cv : ck) + (size_t)h * 33 * 64 + j * 64 + d4;
        float* dst = (half ? cvs : cks) + j * 68 + d4;
        *(float4*)dst = *(const float4*)src;
    }
    float qreg[64];
    {
        const float4* qp4 = (const float4*)(qkv + (size_t)n * QKVD + (h * GQ + grp) * DH);
#pragma unroll
        for (int c = 0; c < 16; ++c) {
            float4 v = qp4[c];
            qreg[4 * c] = v.x; qreg[4 * c + 1] = v.y; qreg[4 * c + 2] = v.z; qreg[4 * c + 3] = v.w;
        }
    }
    __syncthreads();

    // scores: thread (w, g=grp, j = r*16+sub); each cks element broadcast to 4 lanes
#pragma unroll
    for (int r = 0; r < 3; ++r) {
        int j = r * 16 + sub;
        if (j < 33) {
            float acc = 0.f;
#pragma unroll
            for (int d = 0; d < 64; ++d) acc = fmaf(qreg[d], cks[j * 68 + d], acc);
            sims[(w * 4 + grp) * 36 + j] = acc * SCALE;
        }
    }
    // (wave-private LDS; compiler inserts lgkm waits)

    // importance softmax + top-k (exact same math/order as before; expf kept)
    float ival = NEGINF;
    if (lane < 32)
        ival = 0.25f * (sims[(w * 4 + 0) * 36 + 1 + lane] + sims[(w * 4 + 1) * 36 + 1 + lane] +
                        sims[(w * 4 + 2) * 36 + 1 + lane] + sims[(w * 4 + 3) * 36 + 1 + lane]);
    float m = ival;
    for (int off = 32; off; off >>= 1) m = fmaxf(m, __shfl_xor(m, off));
    float e = (lane < 32) ? expf(ival - m) : 0.f;
    float sum = e;
    for (int off = 32; off; off >>= 1) sum += __shfl_xor(sum, off);
    float p = (lane < 32) ? e / sum : NEGINF;

    float v = p;
    int base = (h * NTOK + n) * 9;
    for (int t = 0; t < NSEL; ++t) {
        float bv = v; int bi = lane;
        for (int off = 32; off; off >>= 1) {
            float ov = __shfl_xor(bv, off);
            int   oi = __shfl_xor(bi, off);
            if (ov > bv || (ov == bv && oi < bi)) { bv = ov; bi = oi; }
        }
        if (lane == 0) { sel[base + t] = bi; selmask[base + t] = (bv > 1e-10f) ? 1 : 0; }
        if (lane == bi) v = NEGINF;
    }
    if (lane == 0) { sel[base + NSEL] = n >> 5; selmask[base + NSEL] = 1; }

    // per-g softmax over 33 (overwrite sims with probabilities)
#pragma unroll
    for (int g = 0; g < 4; ++g) {
        float sv = (lane < 33) ? sims[(w * 4 + g) * 36 + lane] : NEGINF;
        float mm = sv;
        for (int off = 32; off; off >>= 1) mm = fmaxf(mm, __shfl_xor(mm, off));
        float ee = (lane < 33) ? __expf(sv - mm) : 0.f;
        float ssum = ee;
        for (int off = 32; off; off >>= 1) ssum += __shfl_xor(ssum, off);
        if (lane < 33) sims[(w * 4 + g) * 36 + lane] = ee / ssum;
    }

    // PV: thread (w, g=grp, d=sub*4..+3); cvs float4 broadcast to 4 lanes
    f32x4 o = (f32x4){0.f, 0.f, 0.f, 0.f};
#pragma unroll
    for (int j = 0; j < 33; ++j) {
        float a = sims[(w * 4 + grp) * 36 + j];
        f32x4 vv = *(const f32x4*)&cvs[j * 68 + sub * 4];
        o += a * vv;
    }
    *(f32x4*)&c_out[(((size_t)(h * GQ + grp)) * NTOK + n) * DH + sub * 4] = o;
}

// ---------------------------------------------------------------------------
// K9: fine attention, online softmax over 5 block-pairs, K+V co-staged.
// Role-remapped lanes: score (g=grp, jj=w*16+sub), PV (g=grp, d=w*16+sub);
// softmax update per wave (wave w owns g=w). All LDS reads broadcast/2-way.
// ---------------------------------------------------------------------------
__global__ __launch_bounds__(256)
void fattn_kernel(const float* __restrict__ qr, const float* __restrict__ kr,
                  const float* __restrict__ vr, const int* __restrict__ sel,
                  const int* __restrict__ selmask, float* __restrict__ f_out) {
    int n = blockIdx.x, h = blockIdx.y;
    int tid = threadIdx.x;
    int w = tid >> 6, lane = tid & 63;
    int grp = lane >> 4, sub = lane & 15;
    __shared__ float Ks[64 * 68];
    __shared__ float Vs[64 * 68];
    __shared__ float ssc[4 * 68];
    __shared__ float ps[4 * 68];
    __shared__ float alphas[4], ls[4];
    __shared__ int sel_s[9], msk_s[9];

    if (tid < 9) {
        sel_s[tid] = sel[(h * NTOK + n) * 9 + tid];
        msk_s[tid] = selmask[(h * NTOK + n) * 9 + tid];
    }
    float qreg[64];
    {
        const float4* qp4 = (const float4*)(qr + (((size_t)(h * GQ + grp)) * NTOK + n) * DH);
#pragma unroll
        for (int c = 0; c < 16; ++c) {
            float4 vv = qp4[c];
            qreg[4 * c] = vv.x; qreg[4 * c + 1] = vv.y; qreg[4 * c + 2] = vv.z; qreg[4 * c + 3] = vv.w;
        }
    }
    float o = 0.f;
    float m_run = -3.402823466e38f, l_run = 0.f;
    __syncthreads();

    for (int bp = 0; bp < 5; ++bp) {
        int nrow = (bp < 4) ? 64 : 32;
        for (int t4 = tid; t4 < nrow * 16; t4 += 256) {
            int row = t4 >> 4, d4 = (t4 & 15) * 4;
            int blk = sel_s[bp * 2 + (row >> 5)];
            int j = row & 31;
            *(float4*)&Ks[row * 68 + d4] =
                *(const float4*)&kr[((size_t)h * NTOK + blk * BSZ + j) * DH + d4];
            *(float4*)&Vs[row * 68 + d4] =
                *(const float4*)&vr[((size_t)h * NTOK + blk * BSZ + j) * DH + d4];
        }
        __syncthreads();

        // scores: thread -> (g=grp, jj=w*16+sub)
        {
            int jj = w * 16 + sub;
            int b = bp * 2 + (jj >> 5);
            float s = -3.402823466e38f;
            if (jj < nrow && msk_s[b]) {
                float acc = 0.f;
#pragma unroll
                for (int d = 0; d < 64; ++d) acc = fmaf(qreg[d], Ks[jj * 68 + d], acc);
                s = acc * SCALE;
            }
            ssc[grp * 68 + jj] = s;
        }
        __syncthreads();

        // online softmax update: wave w owns g = w, lane = jj
        {
            float sv = ssc[w * 68 + lane];
            float mb = sv;
            for (int off = 32; off; off >>= 1) mb = fmaxf(mb, __shfl_xor(mb, off));
            float m_new = fmaxf(m_run, mb);
            float pp = (sv > -1e37f) ? __expf(sv - m_new) : 0.f;
            float alpha = __expf(m_run - m_new);
            float psum = pp;
            for (int off = 32; off; off >>= 1) psum += __shfl_xor(psum, off);
            l_run = l_run * alpha + psum;
            m_run = m_new;
            ps[w * 68 + lane] = pp;
            if (lane == 0) alphas[w] = alpha;
        }
        __syncthreads();

        // PV: thread -> (g=grp, d=w*16+sub)
        {
            int d = w * 16 + sub;
            o *= alphas[grp];
#pragma unroll
            for (int j2 = 0; j2 < 64; ++j2)
                o = fmaf(ps[grp * 68 + j2], Vs[j2 * 68 + d], o);
        }
        __syncthreads();
    }
    if (lane == 0) ls[w] = l_run;
    __syncthreads();
    int d = w * 16 + sub;
    f_out[(((size_t)(h * GQ + grp)) * NTOK + n) * DH + d] = o / ls[grp];
}

// ---------------------------------------------------------------------------
// K10: gated mix -> split-bf16 TILED (K=DDIM). gates f32 [N][128] padded.
// ---------------------------------------------------------------------------
__global__ void mix_kernel(const float* __restrict__ gates, const float* __restrict__ c_out,
                           const float* __restrict__ f_out,
                           u16* __restrict__ mixhi, u16* __restrict__ mixlo) {
    int idx = blockIdx.x * 256 + threadIdx.x;   // 1024*1024/8 = 131072
    int col = (idx & 127) * 8;
    int n = idx >> 7;
    int hd = col >> 6, d = col & 63;
    float g0 = gates[(size_t)n * 128 + hd * 2];
    float g1 = gates[(size_t)n * 128 + hd * 2 + 1];
    size_t hoff = (((size_t)hd) * NTOK + n) * DH + d;
    u16x8 h, l;
#pragma unroll
    for (int j = 0; j < 8; ++j) {
        float v = g0 * c_out[hoff + j] + g1 * f_out[hoff + j];
        u16 hh = f2bf(v);
        h[j] = hh;
        l[j] = f2bf(v - bf2f(hh));
    }
    size_t ob = tiled_off(n, col, DDIM);
    *(u16x8*)&mixhi[ob] = h;
    *(u16x8*)&mixlo[ob] = l;
}

// ---------------------------------------------------------------------------
extern "C" void kernel_launch(void* const* d_in, const int* in_sizes, int n_in,
                              void* d_out, int out_size, void* d_ws, size_t ws_size,
                              hipStream_t stream) {
    const float* inp    = (const float*)d_in[0];
    const float* g_norm = (const float*)d_in[1];
    const float* w_qkv  = (const float*)d_in[2];
    const float* mem_kv = (const float*)d_in[3];
    const float* k_pos  = (const float*)d_in[4];
    const float* v_pos  = (const float*)d_in[5];
    const float* k_w1   = (const float*)d_in[6];
    const float* k_b1   = (const float*)d_in[7];
    const float* k_w2   = (const float*)d_in[8];
    const float* k_b2   = (const float*)d_in[9];
    const float* v_w1   = (const float*)d_in[10];
    const float* v_b1   = (const float*)d_in[11];
    const float* v_w2   = (const float*)d_in[12];
    const float* v_b2   = (const float*)d_in[13];
    const float* gate_w = (const float*)d_in[14];
    const float* gate_b = (const float*)d_in[15];
    const float* w_out  = (const float*)d_in[16];
    float* out = (float*)d_out;

    char* wsb = (char*)d_ws;
    size_t off = 0;
    auto alloc = [&](size_t bytes) -> void* {
        void* p = wsb + off;
        off = (off + bytes + 255) & ~(size_t)255;
        return p;
    };
    u16*   xhi    = (u16*)  alloc((size_t)NTOK * DDIM * 2);
    u16*   xlo    = (u16*)  alloc((size_t)NTOK * DDIM * 2);
    float* qkvb   = (float*)alloc((size_t)NTOK * QKVD * 4);
    u16*   wqThi  = (u16*)  alloc((size_t)QKVD * DDIM * 2);
    u16*   wqTlo  = (u16*)  alloc((size_t)QKVD * DDIM * 2);
    u16*   kw1Thi = (u16*)  alloc((size_t)HIDN * CDIM * 2);
    u16*   kw1Tlo = (u16*)  alloc((size_t)HIDN * CDIM * 2);
    u16*   vw1Thi = (u16*)  alloc((size_t)HIDN * CDIM * 2);
    u16*   vw1Tlo = (u16*)  alloc((size_t)HIDN * CDIM * 2);
    u16*   woThi  = (u16*)  alloc((size_t)DDIM * DDIM * 2);
    u16*   gwThi  = (u16*)  alloc((size_t)128 * DDIM * 2);
    u16*   gwTlo  = (u16*)  alloc((size_t)128 * DDIM * 2);
    float* gbp    = (float*)alloc(128 * 4);
    u16*   kw2Thi = (u16*)  alloc((size_t)128 * HIDN * 2);
    u16*   kw2Tlo = (u16*)  alloc((size_t)128 * HIDN * 2);
    float* kb2p   = (float*)alloc(128 * 4);
    u16*   vw2Thi = (u16*)  alloc((size_t)128 * HIDN * 2);
    u16*   vw2Tlo = (u16*)  alloc((size_t)128 * HIDN * 2);
    float* vb2p   = (float*)alloc(128 * 4);
    u16*   cinkhi = (u16*)  alloc((size_t)128 * CDIM * 2);
    u16*   cinklo = (u16*)  alloc((size_t)128 * CDIM * 2);
    u16*   cinvhi = (u16*)  alloc((size_t)128 * CDIM * 2);
    u16*   cinvlo = (u16*)  alloc((size_t)128 * CDIM * 2);
    u16*   hidkhi = (u16*)  alloc((size_t)128 * HIDN * 2);
    u16*   hidklo = (u16*)  alloc((size_t)128 * HIDN * 2);
    u16*   hidvhi = (u16*)  alloc((size_t)128 * HIDN * 2);
    u16*   hidvlo = (u16*)  alloc((size_t)128 * HIDN * 2);
    float* Pg     = (float*)alloc((size_t)8 * NTOK * 128 * 4);
    float* Pm1k   = (float*)alloc((size_t)4 * 128 * HIDN * 4);
    float* Pm1v   = (float*)alloc((size_t)4 * 128 * HIDN * 4);
    float* Pm2k   = (float*)alloc((size_t)8 * 128 * 128 * 4);
    float* Pm2v   = (float*)alloc((size_t)8 * 128 * 128 * 4);
    float* ckp    = (float*)alloc((size_t)128 * 128 * 4);
    float* cvp    = (float*)alloc((size_t)128 * 128 * 4);
    float* ck     = (float*)alloc((size_t)KVH * 33 * DH * 4);
    float* cv     = (float*)alloc((size_t)KVH * 33 * DH * 4);
    float* qr     = (float*)alloc((size_t)HEADS * NTOK * DH * 4);
    float* kr     = (float*)alloc((size_t)KVH * NTOK * DH * 4);
    float* vr     = (float*)alloc((size_t)KVH * NTOK * DH * 4);
    float* c_out  = (float*)alloc((size_t)HEADS * NTOK * DH * 4);
    float* f_out  = (float*)alloc((size_t)HEADS * NTOK * DH * 4);
    float* gates  = (float*)alloc((size_t)NTOK * 128 * 4);
    int*   sel    = (int*)  alloc((size_t)KVH * NTOK * 9 * 4);
    int*   selmask= (int*)  alloc((size_t)KVH * NTOK * 9 * 4);
    u16*   mixhi  = (u16*)  alloc((size_t)NTOK * DDIM * 2);
    u16*   mixlo  = (u16*)  alloc((size_t)NTOK * DDIM * 2);

    // weight prep (tiled layouts)
    transpose_split<<<dim3(QKVD / 64, DDIM / 64), 256, 0, stream>>>(w_qkv, wqThi, wqTlo, DDIM, QKVD);
    transpose_split<<<dim3(HIDN / 64, CDIM / 64), 256, 0, stream>>>(k_w1, kw1Thi, kw1Tlo, CDIM, HIDN);
    transpose_split<<<dim3(HIDN / 64, CDIM / 64), 256, 0, stream>>>(v_w1, vw1Thi, vw1Tlo, CDIM, HIDN);
    transpose_split<<<dim3(DDIM / 64, DDIM / 64), 256, 0, stream>>>(w_out, woThi, nullptr, DDIM, DDIM);
    pad_small_tiled<<<(128 * DDIM / 8) / 256, 256, 0, stream>>>(gate_w, gate_b, gwThi, gwTlo, gbp, DDIM, 32, 10);
    pad_small_tiled<<<(128 * HIDN / 8) / 256, 256, 0, stream>>>(k_w2, k_b2, kw2Thi, kw2Tlo, kb2p, HIDN, 64, 11);
    pad_small_tiled<<<(128 * HIDN / 8) / 256, 256, 0, stream>>>(v_w2, v_b2, vw2Thi, vw2Tlo, vb2p, HIDN, 64, 11);

    // 1. RMSNorm -> tiled split-bf16 x
    rmsnorm_kernel<<<NTOK / 2, 256, 0, stream>>>(inp, g_norm, xhi, xlo);
    // 2. qkv = x @ w_qkv (final f32)
    gemm_tiled<3, 0, 1><<<dim3(QKVD / 128, NTOK / 128, 1), 256, 0, stream>>>(
        xhi, xlo, wqThi, wqTlo, nullptr, qkvb,
        xhi, xlo, wqThi, wqTlo, nullptr, qkvb, NTOK, QKVD, DDIM, 1);
    // 3. gates (split-K 8 + sigmoid reduce)
    gemm_tiled<3, 0, 0><<<dim3(1, NTOK / 128, 8), 256, 0, stream>>>(
        xhi, xlo, gwThi, gwTlo, nullptr, Pg,
        xhi, xlo, gwThi, gwTlo, nullptr, Pg, NTOK, 128, DDIM, 8);
    reduce_f32<2><<<dim3(128, 1), 256, 0, stream>>>(Pg, gbp, gates, Pg, gbp, gates, 8, NTOK, 128);
    // 4. compress-MLP inputs (tiled)
    build_cmlp_in<<<128, 256, 0, stream>>>(qkvb, k_pos, v_pos, cinkhi, cinklo, cinvhi, cinvlo);
    // 5. MLP1 (split-K 4, k&v batched; relu+bias+split-tile in reduce)
    gemm_tiled<3, 0, 0><<<dim3(HIDN / 128, 1, 8), 256, 0, stream>>>(
        cinkhi, cinklo, kw1Thi, kw1Tlo, nullptr, Pm1k,
        cinvhi, cinvlo, vw1Thi, vw1Tlo, nullptr, Pm1v, 128, HIDN, CDIM, 4);
    reduce_hid<<<dim3(128, 2), 256, 0, stream>>>(Pm1k, k_b1, hidkhi, hidklo,
                                                 Pm1v, v_b1, hidvhi, hidvlo, 4);
    // 6. MLP2 (split-K 8, k&v batched)
    gemm_tiled<3, 0, 0><<<dim3(1, 1, 16), 256, 0, stream>>>(
        hidkhi, hidklo, kw2Thi, kw2Tlo, nullptr, Pm2k,
        hidvhi, hidvlo, vw2Thi, vw2Tlo, nullptr, Pm2v, 128, 128, HIDN, 8);
    reduce_f32<0><<<dim3(16, 2), 256, 0, stream>>>(Pm2k, kb2p, ckp, Pm2v, vb2p, cvp, 8, 128, 128);
    // 7. concat mem_kv
    assemble_ckcv<<<(KVH * 33 * DH + 255) / 256, 256, 0, stream>>>(mem_kv, ckp, cvp, ck, cv);
    // 8. rotary + packed v
    rotary_kernel<<<(24 * NTOK * 32) / 256, 256, 0, stream>>>(qkvb, qr, kr, vr);
    // 9. compressed attention + selection (4 tokens per block)
    cattn_kernel<<<dim3(NTOK / 4, KVH), 256, 0, stream>>>(qkvb, ck, cv, c_out, sel, selmask);
    // 10. fine attention (online softmax)
    fattn_kernel<<<dim3(NTOK, KVH), 256, 0, stream>>>(qr, kr, vr, sel, selmask, f_out);
    // 11. gated mix -> tiled split-bf16
    mix_kernel<<<(NTOK * DDIM / 8) / 256, 256, 0, stream>>>(gates, c_out, f_out, mixhi, mixlo);
    // 12. output projection (bf16, final)
    gemm_tiled<1, 0, 1><<<dim3(DDIM / 128, NTOK / 128, 1), 256, 0, stream>>>(
        mixhi, mixhi, woThi, woThi, nullptr, out,
        mixhi, mixhi, woThi, woThi, nullptr, out, NTOK, DDIM, DDIM, 1);
}